// Round 1
// baseline (134.413 us; speedup 1.0000x reference)
//
#include <hip/hip_runtime.h>

typedef unsigned long long u64;
typedef unsigned int u32;
typedef unsigned short u16;

#define MSORT 4096     // fallback sort capacity (power of 2)
#define TPB1  1024     // select kernel threads
#define TPBF  1024     // fallback kernel threads
#define BOXCAP 3648    // fallback: boxes staged in LDS (57 KB)
#define KCAP  3072     // select: single-pass key capacity in LDS (24 KB)
#define RSLOT_W 10     // fallback: register slots per wave
#define KPC   300      // kept recorded per class
#define SELCAP 1024
#define PREFR 64       // prefix-NMS rank budget (top-64 per class)

#define WG_SCOPE  __HIP_MEMORY_SCOPE_WORKGROUP
#define DEV_SCOPE __HIP_MEMORY_SCOPE_AGENT

__device__ __forceinline__ float boxArea(float4 b) {
    return __fmul_rn(__fsub_rn(b.z, b.x), __fsub_rn(b.w, b.y));
}

// exact numpy f32 semantics: RN32(inter/uni) > T  <=>  inter (cmp) B*uni in f64
template<bool GE>
__device__ __forceinline__ bool iou_gt(float4 a, float area_a, float4 b, float area_b, double B) {
    float ix1 = fmaxf(a.x, b.x), iy1 = fmaxf(a.y, b.y);
    float ix2 = fminf(a.z, b.z), iy2 = fminf(a.w, b.w);
    float iw  = fmaxf(__fsub_rn(ix2, ix1), 0.0f);
    float ih  = fmaxf(__fsub_rn(iy2, iy1), 0.0f);
    float inter = __fmul_rn(iw, ih);
    float uni   = __fsub_rn(__fadd_rn(area_a, area_b), inter);
    return GE ? ((double)inter >= B * (double)uni) : ((double)inter > B * (double)uni);
}

// monotone bin of a positive-float score's bit pattern (11 bits @ exp 126)
__device__ __forceinline__ int scoreBin(u32 bits) {
    int b = (int)(bits >> 12) - 0x3F000;
    return b < 0 ? 0 : (b > 2047 ? 2047 : b);
}

// ---------------------------------------------------------------------------
// Wave-0 parallel threshold-bin search. Bit-identical result to the former
// serial tid==0 two-level scan: bs = largest bin b such that
// suffix_sum(hist[b..2047]) >= target  (bs = 0 when total < target or edge).
// Replaces ~96 dependent LDS reads (~120 cyc each) with 2 shuffle scans.
// ---------------------------------------------------------------------------
__device__ __forceinline__ void bstar_wave0(
    const u32* __restrict__ hist, int target, int tid,
    int* __restrict__ outBs, int* __restrict__ outTot)
{
    if (tid < 64) {
        int s = 0;
        #pragma unroll
        for (int b = 0; b < 32; b++)                 // rotated: 2-way banks (free)
            s += (int)hist[(tid << 5) + ((b + tid) & 31)];
        #pragma unroll
        for (int d = 1; d < 64; d <<= 1) {           // suffix-inclusive scan
            int v = __shfl_down(s, d, 64);
            if (tid + d < 64) s += v;
        }
        u64 bal = __ballot(s >= target);
        int ch  = bal ? (63 - __builtin_clzll(bal)) : -1;   // largest chunk w/ suffix>=target
        int tot = __shfl(s, 0, 64);
        int bs  = 0;
        if (ch >= 0) {
            int accAbove = (ch < 63) ? __shfl(s, ch + 1, 64) : 0;
            int h = (tid < 32) ? (int)hist[(ch << 5) + tid] : 0;
            #pragma unroll
            for (int d = 1; d < 32; d <<= 1) {
                int v = __shfl_down(h, d, 64);
                if (tid + d < 32) h += v;
            }
            u64 bal2 = __ballot((tid < 32) && (accAbove + h >= target)); // lane 0 always true
            bs = (ch << 5) + (63 - __builtin_clzll(bal2));
        }
        if (tid == 0) { *outBs = bs; if (outTot) *outTot = tot; }
    }
}

// ---------------------------------------------------------------------------
// wave-0 prefix greedy NMS over the top-R (R<=64) candidates, one per lane.
// Exact: greedy decisions for rank j depend only on kept ranks < j.
// Also accumulates kept-score bins into the global theta histogram.
// ---------------------------------------------------------------------------
template<bool GE>
__device__ __forceinline__ int prefix_nms_w0(
    const float* __restrict__ bboxes, const u64* __restrict__ sorted,
    int R, double B, int tid, int c, int N, u64* __restrict__ gkept_c,
    u32* __restrict__ gHist)
{
    u64 key = (tid < R) ? sorted[tid] : 0;
    float4 bx = make_float4(0.f, 0.f, 0.f, 0.f);
    if (tid < R) bx = ((const float4*)bboxes)[(u32)key];
    float ar = boxArea(bx);
    u64 supB = (R >= 64) ? 0ull : (~0ull << R);
    int nk = 0;
    int i = -1;
    for (;;) {
        u64 mask = (i >= 63) ? 0ull : (~0ull << (i + 1));
        u64 alive = ~supB & mask;
        if (!alive) break;
        i = (int)__builtin_ctzll(alive);
        float4 bi;
        bi.x = __shfl(bx.x, i, 64); bi.y = __shfl(bx.y, i, 64);
        bi.z = __shfl(bx.z, i, 64); bi.w = __shfl(bx.w, i, 64);
        float ai = boxArea(bi);
        if (tid == 0) {
            u64 ki = sorted[i];
            u32 flat = (u32)c * (u32)N + (u32)ki;   // top_k ties: lower flat first
            gkept_c[nk] = (ki & 0xFFFFFFFF00000000ull) | (u32)(~flat);
        }
        nk++;
        bool sup = (tid > i) && iou_gt<GE>(bi, ai, bx, ar, B);
        supB |= __ballot(sup);
    }
    // kept lanes = unsuppressed lanes < R: feed the global theta histogram
    if (tid < R && !((supB >> tid) & 1ull))
        atomicAdd(&gHist[scoreBin((u32)(key >> 32))], 1u);
    return nk;
}

// ---------------------------------------------------------------------------
// Kernel 1 (fused select + theta): per class — ONE strided pass over scores,
// top-65 threshold from histogram (wave-parallel search), compact <=256 from
// LDS, rank-by-count, prefix-NMS top-64 -> exact kept' subset. Then the LAST
// block to finish (device-scope fan-in, no grid barrier needed) computes the
// global theta lower bound from gHist and the per-class needFull flags
// (formerly kernel 2).
// ---------------------------------------------------------------------------
__global__ __launch_bounds__(TPB1, 1) void nms_select_kernel(
    const float* __restrict__ bboxes, const float* __restrict__ scores,
    const float* __restrict__ conf_ptr, const float* __restrict__ nms_ptr,
    int N, int C, u64* __restrict__ gkept,
    u32* __restrict__ gK, u32* __restrict__ g65, u32* __restrict__ gPre,
    u32* __restrict__ gHist, u32* __restrict__ gCtl, u32* __restrict__ gDone,
    int Mout)
{
    __shared__ u64 keys[KCAP];            // 24 KB
    __shared__ u32 hist[2048];            // 8 KB
    __shared__ u64 keybuf[256];
    __shared__ u64 sorted[66];
    __shared__ int cntS, ncollS, bstarS, nkS, lastS, thBs, thTot;

    const int tid = threadIdx.x;
    const int c   = blockIdx.x;
    const int cls = c + 1;
    const float conf = *conf_ptr;
    const float nmsT = *nms_ptr;

    for (int b = tid; b < 2048; b += TPB1) hist[b] = 0;
    if (tid < 66) sorted[tid] = 0;
    if (tid == 0) { cntS = 0; ncollS = 0; nkS = 0; }
    __syncthreads();

    // ---- single strided pass: collect keys + histogram
    for (int i = tid; i < N; i += TPB1) {
        float s = scores[(size_t)i * C + cls];
        if (s > conf) {
            int p = atomicAdd(&cntS, 1);
            if (p < KCAP) keys[p] = ((u64)__float_as_uint(s) << 32) | (u32)i;
            atomicAdd(&hist[scoreBin(__float_as_uint(s))], 1u);
        }
    }
    __syncthreads();
    const int K = cntS;
    const bool preOv = (K > KCAP);
    const int target = K < (PREFR + 1) ? K : (PREFR + 1);

    bstar_wave0(hist, target, tid, &bstarS, nullptr);
    __syncthreads();
    const u32 tbits = (bstarS == 0) ? 0u : (((u32)bstarS + 0x3F000u) << 12);

    // ---- compact top candidates from LDS keys (no 2nd global pass)
    const int KL = K < KCAP ? K : KCAP;
    for (int p = tid; p < KL; p += TPB1) {
        u64 k = keys[p];
        if ((u32)(k >> 32) >= tbits) {
            int pos = atomicAdd(&ncollS, 1);
            if (pos < 256) keybuf[pos] = k;
        }
    }
    __syncthreads();
    const int ncoll = ncollS;
    const bool pre = preOv || (ncoll > 256);
    for (int p = ncoll + tid; p < 256; p += TPB1) keybuf[p] = 0;
    __syncthreads();

    u64* gkept_c = gkept + (size_t)c * KPC;
    if (!pre) {
        if (tid < 256) {                       // rank-by-count (keys are unique)
            u64 my = keybuf[tid];
            int rank = 0;
            for (int j = 0; j < 256; j++) rank += (keybuf[j] > my);
            if (my && rank < PREFR + 1) sorted[rank] = my;
        }
        __syncthreads();
        const u32 tb = __float_as_uint(nmsT);
        const float Tn = __uint_as_float(tb + 1u);
        const double B = ((double)nmsT + (double)Tn) * 0.5;
        const bool geCmp = (((tb + 1u) & 1u) == 0u);
        if (tid < 64) {
            int R = ncoll < PREFR ? ncoll : PREFR;
            int nk = geCmp ? prefix_nms_w0<true >(bboxes, sorted, R, B, tid, c, N, gkept_c, gHist)
                           : prefix_nms_w0<false>(bboxes, sorted, R, B, tid, c, N, gkept_c, gHist);
            if (tid == 0) nkS = nk;
        }
        __syncthreads();
        for (int p = nkS + tid; p < KPC; p += TPB1) gkept_c[p] = 0;
    } else {
        for (int p = tid; p < KPC; p += TPB1) gkept_c[p] = 0;
    }
    if (tid == 0) {
        gK[c]   = (u32)K;
        g65[c]  = pre ? 0xFFFFFFFFu : ((ncoll >= PREFR + 1) ? (u32)(sorted[PREFR] >> 32) : 0u);
        gPre[c] = pre ? 1u : 0u;
    }

    // ---- fan-in: last finishing block computes theta + flags (was kernel 2)
    __syncthreads();                 // block's stores drained to L2 (vmcnt(0) at barrier)
    if (tid == 0)                    // release: wbl2 flushes XCD L2 to coherent LLC
        lastS = (__hip_atomic_fetch_add(gDone, 1u, __ATOMIC_ACQ_REL, DEV_SCOPE)
                 == (u32)(gridDim.x - 1)) ? 1 : 0;
    __syncthreads();
    if (!lastS) return;
    __threadfence();                 // acquire for all waves of the last block

    for (int b = tid; b < 2048; b += TPB1) hist[b] = gHist[b];   // 8 KB, not 192 KB
    __syncthreads();
    bstar_wave0(hist, Mout, tid, &thBs, &thTot);
    __syncthreads();
    u32 theta = 0u;
    if (thTot >= Mout && thBs > 0) theta = (((u32)thBs + 0x3F000u) << 12);
    if (tid == 0) gCtl[0] = theta;
    const int nclass = (int)gridDim.x;
    for (int c2 = tid; c2 < nclass; c2 += TPB1) {
        u32 need = gPre[c2];
        if (gK[c2] > PREFR && g65[c2] >= theta) need = 1u;   // theta==0 -> always
        gCtl[1 + c2] = need;
    }
}

// ---------------------------------------------------------------------------
// Fallback greedy (lazy producer/consumer, 4 waves) with stop at theta.
// ---------------------------------------------------------------------------
template<bool GE>
__device__ __forceinline__ u64 sweep_own(
    float4 bi, float area_i, const float4 (&breg)[RSLOT_W],
    const float (&areaj)[RSLOT_W], const float4* __restrict__ boxesLds,
    int base, int nslots, int lane, double B)
{
    u64 ns = 0;
    #pragma unroll
    for (int t = 0; t < RSLOT_W; t++)
        ns |= ((u64)iou_gt<GE>(bi, area_i, breg[t], areaj[t], B)) << (base + t);
    for (int t = RSLOT_W; t < nslots; t++) {
        float4 bj = boxesLds[((base + t) << 6) | lane];
        ns |= ((u64)iou_gt<GE>(bi, area_i, bj, boxArea(bj), B)) << (base + t);
    }
    return ns;
}

template<bool GE>
__device__ __forceinline__ int greedy_full(
    const float4* __restrict__ boxesLds, u16* __restrict__ keptR,
    float4* __restrict__ pubBox, u32* __restrict__ ctl,
    const u32* __restrict__ gsi_c, const float* __restrict__ scores,
    int cls, int C, u32 thetaBits,
    int K, int smax, double B, int lane, int wave)
{
    const int SW   = (smax + 3) >> 2;
    const int base = (wave * SW < smax) ? wave * SW : smax;
    const int end  = (base + SW < smax) ? base + SW : smax;
    const int nslots = end - base;

    float4 breg[RSLOT_W];
    float  areaj[RSLOT_W];
    #pragma unroll
    for (int t = 0; t < RSLOT_W; t++) {
        float4 b = boxesLds[((base + t) << 6) | lane];
        breg[t] = b;
        areaj[t] = boxArea(b);
    }

    u64 sup;
    {
        int t = (lane < K) ? ((K - lane + 63) >> 6) : 0;
        sup = (t >= 64) ? 0ull : (~0ull << t);
    }

    u32 seen = 0;
    if (wave != 0) {
        for (;;) {
            u32 d  = __hip_atomic_load(&ctl[2], __ATOMIC_ACQUIRE, WG_SCOPE);
            u32 cn = __hip_atomic_load(&ctl[0], __ATOMIC_ACQUIRE, WG_SCOPE);
            bool prog = (seen < cn);
            while (seen < cn) {
                float4 bi = pubBox[seen]; seen++;
                sup |= sweep_own<GE>(bi, boxArea(bi), breg, areaj, boxesLds, base, nslots, lane, B);
            }
            if (d) return -1;
            u32 aw = __hip_atomic_load(&ctl[1], __ATOMIC_ACQUIRE, WG_SCOPE);
            if (aw == (u32)wave) {
                u32 cn2 = __hip_atomic_load(&ctl[0], __ATOMIC_ACQUIRE, WG_SCOPE);
                while (seen < cn2) {
                    float4 bi = pubBox[seen]; seen++;
                    sup |= sweep_own<GE>(bi, boxArea(bi), breg, areaj, boxesLds, base, nslots, lane, B);
                }
                break;
            }
            if (!prog) __builtin_amdgcn_s_sleep(1);
        }
    }

    u32 nk = seen;
    const u32 seen0 = seen;
    int scur = base - 1;
    float4 bcur = make_float4(0.f, 0.f, 0.f, 0.f);
    float  acur = 0.f;
    int js = base << 6;

    for (;;) {
        int s = js >> 6;
        while (s > scur) {
            scur++;
            if (scur < end) {
                bcur = boxesLds[(scur << 6) | lane];
                acur = boxArea(bcur);
                u64 bit = 0;
                for (u32 k = seen0; k < nk; k++) {
                    float4 bk = pubBox[k];
                    bit |= ((u64)iou_gt<GE>(bk, boxArea(bk), bcur, acur, B));
                }
                sup |= bit << scur;
            }
        }
        if (scur >= end) {
            if (wave == 3) {
                if (lane == 0) __hip_atomic_store(&ctl[2], 1u, __ATOMIC_RELEASE, WG_SCOPE);
                return (int)nk;
            }
            if (lane == 0) __hip_atomic_store(&ctl[1], (u32)(wave + 1), __ATOMIC_RELEASE, WG_SCOPE);
            return -1;
        }
        u64 bal = __ballot((int)(((~sup) >> scur) & 1ull)) & (~0ull << (js & 63));
        if (bal == 0) { js = (scur + 1) << 6; continue; }
        int i = (scur << 6) + (int)__builtin_ctzll(bal);

        if (thetaBits) {
            u32 idx = gsi_c[i];
            float sc = scores[(size_t)idx * C + cls];
            if (__float_as_uint(sc) < thetaBits) {
                if (lane == 0) __hip_atomic_store(&ctl[2], 1u, __ATOMIC_RELEASE, WG_SCOPE);
                return (int)nk;
            }
        }
        float4 bi = boxesLds[i];
        if (lane == 0) { pubBox[nk] = bi; keptR[nk] = (u16)i; }
        nk++;
        if (nk >= KPC) {
            if (lane == 0) {
                __hip_atomic_store(&ctl[0], nk, __ATOMIC_RELEASE, WG_SCOPE);
                __hip_atomic_store(&ctl[2], 1u, __ATOMIC_RELEASE, WG_SCOPE);
            }
            return (int)nk;
        }
        if (lane == 0) __hip_atomic_store(&ctl[0], nk, __ATOMIC_RELEASE, WG_SCOPE);
        sup |= ((u64)iou_gt<GE>(bi, boxArea(bi), bcur, acur, B)) << scur;
        js = i + 1;
    }
}

// ---------------------------------------------------------------------------
// Kernel 2 (fused full + topk): full per-class NMS for flagged classes only
// (sort @1024 thr, greedy on waves 0-3); non-flagged classes fall through
// quickly. The LAST block to finish (fan-in) runs the global top-Mout
// selection + runtime-sized bitonic sort (formerly kernel 4), reusing LDS.
// ---------------------------------------------------------------------------
__global__ __launch_bounds__(TPBF, 1) void nms_full_topk_kernel(
    const float* __restrict__ bboxes, const float* __restrict__ scores,
    const float* __restrict__ conf_ptr, const float* __restrict__ nms_ptr,
    int N, int C, const u32* __restrict__ gCtl,
    u32* __restrict__ gsi, u64* __restrict__ gkept,
    int Mout, float* __restrict__ out, u32* __restrict__ gDone)
{
    __shared__ __align__(16) char smem[63856];
    __shared__ int cntS, lastS, selCountS, bs4S;

    const int c = blockIdx.x;
    const int tid = threadIdx.x;

    if (gCtl[1 + c] != 0u) {
        u64*    sortbuf  = (u64*)smem;             // [0,32768)
        float4* boxesLds = (float4*)smem;          // [0,58368)
        u16*    keptR    = (u16*)(smem + 58368);
        u32*    ctl      = (u32*)(smem + 58976);
        float4* pubBox   = (float4*)(smem + 58992);

        const int cls = c + 1;
        const float conf = *conf_ptr;
        const float nmsT = *nms_ptr;
        const u32 thetaBits = gCtl[0];

        if (tid == 0) cntS = 0;
        __syncthreads();
        for (int i = tid; i < N; i += TPBF) {
            float s = scores[(size_t)i * C + cls];
            if (s > conf) {
                int p = atomicAdd(&cntS, 1);
                if (p < MSORT) sortbuf[p] = ((u64)__float_as_uint(s) << 32) | (u32)i;
            }
        }
        __syncthreads();
        int K = cntS; if (K > BOXCAP) K = BOXCAP;
        int M = 64; while (M < K) M <<= 1;
        for (int p = K + tid; p < M; p += TPBF) sortbuf[p] = 0;
        __syncthreads();
        for (int kk = 2; kk <= M; kk <<= 1) {
            for (int j = kk >> 1; j > 0; j >>= 1) {
                for (int i = tid; i < M; i += TPBF) {
                    int ixj = i ^ j;
                    if (ixj > i) {
                        u64 a = sortbuf[i], b = sortbuf[ixj];
                        if (((i & kk) == 0) ? (a < b) : (a > b)) { sortbuf[i] = b; sortbuf[ixj] = a; }
                    }
                }
                __syncthreads();
            }
        }
        u32 myIdx[MSORT / TPBF];
        #pragma unroll
        for (int t = 0; t < MSORT / TPBF; t++) myIdx[t] = (u32)sortbuf[t * TPBF + tid];
        __syncthreads();
        u32* gsi_c = gsi + (size_t)c * BOXCAP;
        #pragma unroll
        for (int t = 0; t < MSORT / TPBF; t++) {
            int r = t * TPBF + tid;
            if (r < K) {
                u32 idx = myIdx[t];
                gsi_c[r] = idx;
                boxesLds[r] = ((const float4*)bboxes)[idx];
            }
        }
        if (tid == 0) { ctl[0] = 0; ctl[1] = 0; ctl[2] = 0; }
        __syncthreads();

        if (tid < 256) {
            const int lane = tid & 63;
            const int wave = tid >> 6;
            const u32 tb = __float_as_uint(nmsT);
            const float Tn = __uint_as_float(tb + 1u);
            const double B = ((double)nmsT + (double)Tn) * 0.5;
            const bool geCmp = (((tb + 1u) & 1u) == 0u);
            const int smax = (K + 63) >> 6;

            int ret = geCmp ? greedy_full<true >(boxesLds, keptR, pubBox, ctl, gsi_c, scores, cls, C, thetaBits, K, smax, B, lane, wave)
                            : greedy_full<false>(boxesLds, keptR, pubBox, ctl, gsi_c, scores, cls, C, thetaBits, K, smax, B, lane, wave);
            if (ret >= 0) {
                int kept = ret; if (kept > KPC) kept = KPC;
                u64* gkept_c = gkept + (size_t)c * KPC;
                for (int p = lane; p < kept; p += 64) {
                    int rank = keptR[p];
                    u32 idx = gsi_c[rank];
                    float sc = scores[(size_t)idx * C + cls];
                    u32 flat = (u32)c * (u32)N + idx;
                    gkept_c[p] = ((u64)__float_as_uint(sc) << 32) | (u32)(~flat);
                }
                for (int p = kept + lane; p < KPC; p += 64) gkept_c[p] = 0;
            }
        }
    }

    // ---- fan-in: last finishing block runs global top-Mout (was kernel 4)
    __syncthreads();
    if (tid == 0)
        lastS = (__hip_atomic_fetch_add(gDone, 1u, __ATOMIC_ACQ_REL, DEV_SCOPE)
                 == (u32)(gridDim.x - 1)) ? 1 : 0;
    __syncthreads();
    if (!lastS) return;
    __threadfence();

    u64* sel   = (u64*)smem;                    // 8 KB  (aliases sortbuf, dead now)
    u32* hist4 = (u32*)(smem + 8192);           // 8 KB
    const int total = (int)gridDim.x * KPC;

    for (int b = tid; b < 2048; b += TPBF) hist4[b] = 0;
    if (tid == 0) selCountS = 0;
    __syncthreads();

    for (int t = tid; t < total; t += TPBF) {
        u64 k = gkept[t];
        if (k) atomicAdd(&hist4[scoreBin((u32)(k >> 32))], 1u);
    }
    __syncthreads();

    bstar_wave0(hist4, Mout, tid, &bs4S, nullptr);
    __syncthreads();
    const int bstar = bs4S;

    for (int t = tid; t < total; t += TPBF) {
        u64 k = gkept[t];
        if (k && scoreBin((u32)(k >> 32)) >= bstar) {
            int p = atomicAdd(&selCountS, 1);
            if (p < SELCAP) sel[p] = k;
        }
    }
    __syncthreads();
    int cnt = selCountS; if (cnt > SELCAP) cnt = SELCAP;
    int SM = 512; while (SM < cnt) SM <<= 1;       // runtime-sized (>= Mout)
    for (int p = cnt + tid; p < SM; p += TPBF) sel[p] = 0;
    __syncthreads();

    for (int kk = 2; kk <= SM; kk <<= 1) {
        for (int j = kk >> 1; j > 0; j >>= 1) {
            for (int i = tid; i < SM; i += TPBF) {
                int ixj = i ^ j;
                if (ixj > i) {
                    u64 a = sel[i], b = sel[ixj];
                    if (((i & kk) == 0) ? (a < b) : (a > b)) { sel[i] = b; sel[ixj] = a; }
                }
            }
            __syncthreads();
        }
    }

    for (int t = tid; t < Mout; t += TPBF) {
        u64 k = (t < SM) ? sel[t] : 0;
        float px1 = 0.f, py1 = 0.f, px2 = 0.f, py2 = 0.f, ps = 0.f, plab = -1.0f;
        if (k) {
            float s  = __uint_as_float((u32)(k >> 32));
            u32 flat = ~((u32)k);
            int cc   = (int)(flat / (u32)N);
            int box  = (int)(flat - (u32)cc * (u32)N);
            float4 bb = ((const float4*)bboxes)[box];
            px1 = bb.x; py1 = bb.y; px2 = bb.z; py2 = bb.w; ps = s;
            plab = (float)(cc + 1);
        }
        out[t * 5 + 0] = px1;
        out[t * 5 + 1] = py1;
        out[t * 5 + 2] = px2;
        out[t * 5 + 3] = py2;
        out[t * 5 + 4] = ps;
        out[Mout * 5 + t] = plab;
    }
}

extern "C" void kernel_launch(void* const* d_in, const int* in_sizes, int n_in,
                              void* d_out, int out_size, void* d_ws, size_t ws_size,
                              hipStream_t stream) {
    const float* bboxes = (const float*)d_in[0];
    const float* scores = (const float*)d_in[1];
    const float* conf   = (const float*)d_in[2];
    const float* nmsT   = (const float*)d_in[3];

    const int N    = in_sizes[0] / 4;        // 5000
    const int C    = in_sizes[1] / N;        // 81
    const int nc   = C - 1;                  // 80
    const int Mout = out_size / 6;           // 300

    // ws layout: [gsi][gkept][gK|g65|gPre][gCtl][gHist|gDone]
    char* wsb = (char*)d_ws;
    size_t off = 0;
    u32* gsi   = (u32*)(wsb + off); off += (size_t)nc * BOXCAP * sizeof(u32);
    u64* gkept = (u64*)(wsb + off); off += (size_t)nc * KPC * sizeof(u64);
    u32* gK    = (u32*)(wsb + off); off += (size_t)((nc + 1) & ~1) * sizeof(u32);
    u32* g65   = (u32*)(wsb + off); off += (size_t)((nc + 1) & ~1) * sizeof(u32);
    u32* gPre  = (u32*)(wsb + off); off += (size_t)((nc + 1) & ~1) * sizeof(u32);
    u32* gCtl  = (u32*)(wsb + off); off += (size_t)((1 + nc + 1) & ~1) * sizeof(u32);
    u32* gHist = (u32*)(wsb + off); off += 2048 * sizeof(u32);
    u32* gDone = (u32*)(wsb + off); off += 2 * sizeof(u32);

    // zero the theta histogram + the two fan-in counters (8.2 KB memset node;
    // capture-legal, replays each graph launch)
    hipMemsetAsync(gHist, 0, (2048 + 2) * sizeof(u32), stream);

    nms_select_kernel<<<nc, TPB1, 0, stream>>>(bboxes, scores, conf, nmsT, N, C,
                                               gkept, gK, g65, gPre, gHist, gCtl,
                                               gDone, Mout);
    nms_full_topk_kernel<<<nc, TPBF, 0, stream>>>(bboxes, scores, conf, nmsT, N, C,
                                                  gCtl, gsi, gkept, Mout,
                                                  (float*)d_out, gDone + 1);
}

// Round 2
// 124.555 us; speedup vs baseline: 1.0791x; 1.0791x over previous
//
#include <hip/hip_runtime.h>

typedef unsigned long long u64;
typedef unsigned int u32;
typedef unsigned short u16;

#define MSORT 4096     // fallback sort capacity (power of 2)
#define TPB1  1024     // select kernel threads
#define TPBF  1024     // fallback kernel threads
#define BOXCAP 3648    // fallback: boxes staged in LDS (57 KB)
#define KCAP  3072     // select: single-pass key capacity in LDS (24 KB)
#define RSLOT_W 10     // fallback: register slots per wave
#define KPC   300      // kept recorded per class
#define SELCAP 1024
#define PREFR 64       // prefix-NMS rank budget (top-64 per class)
#define TBOX  128      // transpose: boxes per tile (128*81*4 = 41.5 KB LDS)

#define WG_SCOPE __HIP_MEMORY_SCOPE_WORKGROUP

__device__ __forceinline__ float boxArea(float4 b) {
    return __fmul_rn(__fsub_rn(b.z, b.x), __fsub_rn(b.w, b.y));
}

// exact numpy f32 semantics: RN32(inter/uni) > T  <=>  inter (cmp) B*uni in f64
template<bool GE>
__device__ __forceinline__ bool iou_gt(float4 a, float area_a, float4 b, float area_b, double B) {
    float ix1 = fmaxf(a.x, b.x), iy1 = fmaxf(a.y, b.y);
    float ix2 = fminf(a.z, b.z), iy2 = fminf(a.w, b.w);
    float iw  = fmaxf(__fsub_rn(ix2, ix1), 0.0f);
    float ih  = fmaxf(__fsub_rn(iy2, iy1), 0.0f);
    float inter = __fmul_rn(iw, ih);
    float uni   = __fsub_rn(__fadd_rn(area_a, area_b), inter);
    return GE ? ((double)inter >= B * (double)uni) : ((double)inter > B * (double)uni);
}

// monotone bin of a positive-float score's bit pattern (11 bits @ exp 126)
__device__ __forceinline__ int scoreBin(u32 bits) {
    int b = (int)(bits >> 12) - 0x3F000;
    return b < 0 ? 0 : (b > 2047 ? 2047 : b);
}

// ---------------------------------------------------------------------------
// Wave-0 parallel threshold-bin search (validated round 1, bit-identical to
// the serial two-level scan): bs = largest bin b with
// suffix_sum(hist[b..2047]) >= target (0 at edge / when total < target).
// ---------------------------------------------------------------------------
__device__ __forceinline__ void bstar_wave0(
    const u32* __restrict__ hist, int target, int tid,
    int* __restrict__ outBs, int* __restrict__ outTot)
{
    if (tid < 64) {
        int s = 0;
        #pragma unroll
        for (int b = 0; b < 32; b++)                 // rotated: 2-way banks (free)
            s += (int)hist[(tid << 5) + ((b + tid) & 31)];
        #pragma unroll
        for (int d = 1; d < 64; d <<= 1) {           // suffix-inclusive scan
            int v = __shfl_down(s, d, 64);
            if (tid + d < 64) s += v;
        }
        u64 bal = __ballot(s >= target);
        int ch  = bal ? (63 - __builtin_clzll(bal)) : -1;   // largest chunk w/ suffix>=target
        int tot = __shfl(s, 0, 64);
        int bs  = 0;
        if (ch >= 0) {
            int accAbove = (ch < 63) ? __shfl(s, ch + 1, 64) : 0;
            int h = (tid < 32) ? (int)hist[(ch << 5) + tid] : 0;
            #pragma unroll
            for (int d = 1; d < 32; d <<= 1) {
                int v = __shfl_down(h, d, 64);
                if (tid + d < 32) h += v;
            }
            u64 bal2 = __ballot((tid < 32) && (accAbove + h >= target)); // lane 0 always true
            bs = (ch << 5) + (63 - __builtin_clzll(bal2));
        }
        if (tid == 0) { *outBs = bs; if (outTot) *outTot = tot; }
    }
}

// ---------------------------------------------------------------------------
// Kernel 0: coalesced transpose scores[N][C] -> scoresT[C][N] via LDS tile.
// Block 0 also zeroes the global theta histogram (replaces memset node).
// ---------------------------------------------------------------------------
__global__ __launch_bounds__(1024) void transpose_kernel(
    const float* __restrict__ scores, int N, int C,
    float* __restrict__ scoresT, u32* __restrict__ gHist)
{
    __shared__ float tile[TBOX * 81];
    const int tid = threadIdx.x;
    const int b0  = blockIdx.x * TBOX;
    const int nb  = (N - b0 < TBOX) ? (N - b0) : TBOX;
    const int tot = nb * C;
    for (int e = tid; e < tot; e += 1024)            // coalesced read
        tile[e] = scores[(size_t)b0 * C + e];
    __syncthreads();
    if (nb == TBOX) {
        const int wtot = C << 7;
        for (int o = tid; o < wtot; o += 1024) {     // coalesced write per class row
            int cls = o >> 7, j = o & (TBOX - 1);
            scoresT[(size_t)cls * N + b0 + j] = tile[j * C + cls];
        }
    } else {
        const int wtot = C * nb;
        for (int o = tid; o < wtot; o += 1024) {
            int cls = o / nb, j = o - cls * nb;
            scoresT[(size_t)cls * N + b0 + j] = tile[j * C + cls];
        }
    }
    if (blockIdx.x == 0)
        for (int h = tid; h < 2048; h += 1024) gHist[h] = 0;
}

// ---------------------------------------------------------------------------
// wave-0 prefix greedy NMS over the top-R (R<=64) candidates, one per lane.
// Exact: greedy decisions for rank j depend only on kept ranks < j.
// Accumulates kept-score bins into the global theta histogram (validated r1).
// ---------------------------------------------------------------------------
template<bool GE>
__device__ __forceinline__ int prefix_nms_w0(
    const float* __restrict__ bboxes, const u64* __restrict__ sorted,
    int R, double B, int tid, int c, int N, u64* __restrict__ gkept_c,
    u32* __restrict__ gHist)
{
    u64 key = (tid < R) ? sorted[tid] : 0;
    float4 bx = make_float4(0.f, 0.f, 0.f, 0.f);
    if (tid < R) bx = ((const float4*)bboxes)[(u32)key];
    float ar = boxArea(bx);
    u64 supB = (R >= 64) ? 0ull : (~0ull << R);
    int nk = 0;
    int i = -1;
    for (;;) {
        u64 mask = (i >= 63) ? 0ull : (~0ull << (i + 1));
        u64 alive = ~supB & mask;
        if (!alive) break;
        i = (int)__builtin_ctzll(alive);
        float4 bi;
        bi.x = __shfl(bx.x, i, 64); bi.y = __shfl(bx.y, i, 64);
        bi.z = __shfl(bx.z, i, 64); bi.w = __shfl(bx.w, i, 64);
        float ai = boxArea(bi);
        if (tid == 0) {
            u64 ki = sorted[i];
            u32 flat = (u32)c * (u32)N + (u32)ki;   // top_k ties: lower flat first
            gkept_c[nk] = (ki & 0xFFFFFFFF00000000ull) | (u32)(~flat);
        }
        nk++;
        bool sup = (tid > i) && iou_gt<GE>(bi, ai, bx, ar, B);
        supB |= __ballot(sup);
    }
    if (tid < R && !((supB >> tid) & 1ull))
        atomicAdd(&gHist[scoreBin((u32)(key >> 32))], 1u);
    return nk;
}

// ---------------------------------------------------------------------------
// Kernel 1: per class — ONE coalesced float4 pass over scoresT row (ballot-
// aggregated compaction + histogram), top-65 threshold from histogram,
// compact <=256 from LDS, rank-by-count, prefix-NMS top-64.
// ---------------------------------------------------------------------------
__global__ __launch_bounds__(TPB1, 1) void nms_select_kernel(
    const float* __restrict__ bboxes, const float* __restrict__ scoresT,
    const float* __restrict__ conf_ptr, const float* __restrict__ nms_ptr,
    int N, u64* __restrict__ gkept,
    u32* __restrict__ gK, u32* __restrict__ g65, u32* __restrict__ gPre,
    u32* __restrict__ gHist)
{
    __shared__ u64 keys[KCAP];            // 24 KB
    __shared__ u32 hist[2048];            // 8 KB
    __shared__ u64 keybuf[256];
    __shared__ u64 sorted[66];
    __shared__ int cntS, ncollS, bstarS, nkS;

    const int tid  = threadIdx.x;
    const int lane = tid & 63;
    const int c    = blockIdx.x;
    const int cls  = c + 1;
    const float conf = *conf_ptr;
    const float nmsT = *nms_ptr;

    for (int b = tid; b < 2048; b += TPB1) hist[b] = 0;
    if (tid < 66) sorted[tid] = 0;
    if (tid == 0) { cntS = 0; ncollS = 0; nkS = 0; }
    __syncthreads();

    // ---- single coalesced pass: keys -> LDS + histogram (1 atomic per wave)
    const float* rowT = scoresT + (size_t)cls * N;
    const float4* rowT4 = (const float4*)rowT;
    const int N4 = N >> 2;
    for (int i4 = tid; i4 < N4; i4 += TPB1) {
        float4 s4 = rowT4[i4];
        #pragma unroll
        for (int j = 0; j < 4; j++) {
            float s = (j == 0) ? s4.x : (j == 1) ? s4.y : (j == 2) ? s4.z : s4.w;
            bool pass = (s > conf);
            u64 m = __ballot(pass);
            if (m) {
                int leader = (int)__builtin_ctzll(m);
                int base = 0;
                if (lane == leader) base = atomicAdd(&cntS, __popcll(m));
                base = __shfl(base, leader, 64);
                if (pass) {
                    int p = base + (int)__popcll(m & ((1ull << lane) - 1ull));
                    if (p < KCAP)
                        keys[p] = ((u64)__float_as_uint(s) << 32) | (u32)((i4 << 2) + j);
                    atomicAdd(&hist[scoreBin(__float_as_uint(s))], 1u);
                }
            }
        }
    }
    for (int i = (N4 << 2) + tid; i < N; i += TPB1) {   // tail (empty when N%4==0)
        float s = rowT[i];
        if (s > conf) {
            int p = atomicAdd(&cntS, 1);
            if (p < KCAP) keys[p] = ((u64)__float_as_uint(s) << 32) | (u32)i;
            atomicAdd(&hist[scoreBin(__float_as_uint(s))], 1u);
        }
    }
    __syncthreads();
    const int K = cntS;
    const bool preOv = (K > KCAP);
    const int target = K < (PREFR + 1) ? K : (PREFR + 1);

    bstar_wave0(hist, target, tid, &bstarS, nullptr);
    __syncthreads();
    const u32 tbits = (bstarS == 0) ? 0u : (((u32)bstarS + 0x3F000u) << 12);

    // ---- compact top candidates from LDS keys (no 2nd global pass)
    const int KL = K < KCAP ? K : KCAP;
    for (int p = tid; p < KL; p += TPB1) {
        u64 k = keys[p];
        if ((u32)(k >> 32) >= tbits) {
            int pos = atomicAdd(&ncollS, 1);
            if (pos < 256) keybuf[pos] = k;
        }
    }
    __syncthreads();
    const int ncoll = ncollS;
    const bool pre = preOv || (ncoll > 256);
    for (int p = ncoll + tid; p < 256; p += TPB1) keybuf[p] = 0;
    __syncthreads();

    u64* gkept_c = gkept + (size_t)c * KPC;
    if (!pre) {
        if (tid < 256) {                       // rank-by-count (keys are unique)
            u64 my = keybuf[tid];
            int rank = 0;
            for (int j = 0; j < 256; j++) rank += (keybuf[j] > my);
            if (my && rank < PREFR + 1) sorted[rank] = my;
        }
        __syncthreads();
        const u32 tb = __float_as_uint(nmsT);
        const float Tn = __uint_as_float(tb + 1u);
        const double B = ((double)nmsT + (double)Tn) * 0.5;
        const bool geCmp = (((tb + 1u) & 1u) == 0u);
        if (tid < 64) {
            int R = ncoll < PREFR ? ncoll : PREFR;
            int nk = geCmp ? prefix_nms_w0<true >(bboxes, sorted, R, B, tid, c, N, gkept_c, gHist)
                           : prefix_nms_w0<false>(bboxes, sorted, R, B, tid, c, N, gkept_c, gHist);
            if (tid == 0) nkS = nk;
        }
        __syncthreads();
        for (int p = nkS + tid; p < KPC; p += TPB1) gkept_c[p] = 0;
    } else {
        for (int p = tid; p < KPC; p += TPB1) gkept_c[p] = 0;
    }
    if (tid == 0) {
        gK[c]   = (u32)K;
        g65[c]  = pre ? 0xFFFFFFFFu : ((ncoll >= PREFR + 1) ? (u32)(sorted[PREFR] >> 32) : 0u);
        gPre[c] = pre ? 1u : 0u;
    }
}

// ---------------------------------------------------------------------------
// Kernel 2: theta lower bound from the 8 KB global kept-histogram + per-class
// needFull flags. gCtl[0]=thetaBits, gCtl[1+c]=needFull.
// ---------------------------------------------------------------------------
__global__ __launch_bounds__(1024) void nms_theta_kernel(
    const u32* __restrict__ gHist, const u32* __restrict__ gK,
    const u32* __restrict__ g65, const u32* __restrict__ gPre,
    int nc, int Mout, u32* __restrict__ gCtl)
{
    __shared__ u32 hist[2048];
    __shared__ int thBs, thTot;
    const int tid = threadIdx.x;
    for (int b = tid; b < 2048; b += 1024) hist[b] = gHist[b];
    __syncthreads();
    bstar_wave0(hist, Mout, tid, &thBs, &thTot);
    __syncthreads();
    u32 theta = 0u;
    if (thTot >= Mout && thBs > 0) theta = (((u32)thBs + 0x3F000u) << 12);
    if (tid == 0) gCtl[0] = theta;
    for (int c2 = tid; c2 < nc; c2 += 1024) {
        u32 need = gPre[c2];
        if (gK[c2] > PREFR && g65[c2] >= theta) need = 1u;   // theta==0 -> always
        gCtl[1 + c2] = need;
    }
}

// ---------------------------------------------------------------------------
// Fallback greedy (lazy producer/consumer, 4 waves) with stop at theta.
// ---------------------------------------------------------------------------
template<bool GE>
__device__ __forceinline__ u64 sweep_own(
    float4 bi, float area_i, const float4 (&breg)[RSLOT_W],
    const float (&areaj)[RSLOT_W], const float4* __restrict__ boxesLds,
    int base, int nslots, int lane, double B)
{
    u64 ns = 0;
    #pragma unroll
    for (int t = 0; t < RSLOT_W; t++)
        ns |= ((u64)iou_gt<GE>(bi, area_i, breg[t], areaj[t], B)) << (base + t);
    for (int t = RSLOT_W; t < nslots; t++) {
        float4 bj = boxesLds[((base + t) << 6) | lane];
        ns |= ((u64)iou_gt<GE>(bi, area_i, bj, boxArea(bj), B)) << (base + t);
    }
    return ns;
}

template<bool GE>
__device__ __forceinline__ int greedy_full(
    const float4* __restrict__ boxesLds, u16* __restrict__ keptR,
    float4* __restrict__ pubBox, u32* __restrict__ ctl,
    const u32* __restrict__ gsi_c, const float* __restrict__ rowT,
    u32 thetaBits,
    int K, int smax, double B, int lane, int wave)
{
    const int SW   = (smax + 3) >> 2;
    const int base = (wave * SW < smax) ? wave * SW : smax;
    const int end  = (base + SW < smax) ? base + SW : smax;
    const int nslots = end - base;

    float4 breg[RSLOT_W];
    float  areaj[RSLOT_W];
    #pragma unroll
    for (int t = 0; t < RSLOT_W; t++) {
        float4 b = boxesLds[((base + t) << 6) | lane];
        breg[t] = b;
        areaj[t] = boxArea(b);
    }

    u64 sup;
    {
        int t = (lane < K) ? ((K - lane + 63) >> 6) : 0;
        sup = (t >= 64) ? 0ull : (~0ull << t);
    }

    u32 seen = 0;
    if (wave != 0) {
        for (;;) {
            u32 d  = __hip_atomic_load(&ctl[2], __ATOMIC_ACQUIRE, WG_SCOPE);
            u32 cn = __hip_atomic_load(&ctl[0], __ATOMIC_ACQUIRE, WG_SCOPE);
            bool prog = (seen < cn);
            while (seen < cn) {
                float4 bi = pubBox[seen]; seen++;
                sup |= sweep_own<GE>(bi, boxArea(bi), breg, areaj, boxesLds, base, nslots, lane, B);
            }
            if (d) return -1;
            u32 aw = __hip_atomic_load(&ctl[1], __ATOMIC_ACQUIRE, WG_SCOPE);
            if (aw == (u32)wave) {
                u32 cn2 = __hip_atomic_load(&ctl[0], __ATOMIC_ACQUIRE, WG_SCOPE);
                while (seen < cn2) {
                    float4 bi = pubBox[seen]; seen++;
                    sup |= sweep_own<GE>(bi, boxArea(bi), breg, areaj, boxesLds, base, nslots, lane, B);
                }
                break;
            }
            if (!prog) __builtin_amdgcn_s_sleep(1);
        }
    }

    u32 nk = seen;
    const u32 seen0 = seen;
    int scur = base - 1;
    float4 bcur = make_float4(0.f, 0.f, 0.f, 0.f);
    float  acur = 0.f;
    int js = base << 6;

    for (;;) {
        int s = js >> 6;
        while (s > scur) {
            scur++;
            if (scur < end) {
                bcur = boxesLds[(scur << 6) | lane];
                acur = boxArea(bcur);
                u64 bit = 0;
                for (u32 k = seen0; k < nk; k++) {
                    float4 bk = pubBox[k];
                    bit |= ((u64)iou_gt<GE>(bk, boxArea(bk), bcur, acur, B));
                }
                sup |= bit << scur;
            }
        }
        if (scur >= end) {
            if (wave == 3) {
                if (lane == 0) __hip_atomic_store(&ctl[2], 1u, __ATOMIC_RELEASE, WG_SCOPE);
                return (int)nk;
            }
            if (lane == 0) __hip_atomic_store(&ctl[1], (u32)(wave + 1), __ATOMIC_RELEASE, WG_SCOPE);
            return -1;
        }
        u64 bal = __ballot((int)(((~sup) >> scur) & 1ull)) & (~0ull << (js & 63));
        if (bal == 0) { js = (scur + 1) << 6; continue; }
        int i = (scur << 6) + (int)__builtin_ctzll(bal);

        if (thetaBits) {
            u32 idx = gsi_c[i];
            float sc = rowT[idx];                    // 20 KB row: L1/L2-hit
            if (__float_as_uint(sc) < thetaBits) {
                if (lane == 0) __hip_atomic_store(&ctl[2], 1u, __ATOMIC_RELEASE, WG_SCOPE);
                return (int)nk;
            }
        }
        float4 bi = boxesLds[i];
        if (lane == 0) { pubBox[nk] = bi; keptR[nk] = (u16)i; }
        nk++;
        if (nk >= KPC) {
            if (lane == 0) {
                __hip_atomic_store(&ctl[0], nk, __ATOMIC_RELEASE, WG_SCOPE);
                __hip_atomic_store(&ctl[2], 1u, __ATOMIC_RELEASE, WG_SCOPE);
            }
            return (int)nk;
        }
        if (lane == 0) __hip_atomic_store(&ctl[0], nk, __ATOMIC_RELEASE, WG_SCOPE);
        sup |= ((u64)iou_gt<GE>(bi, boxArea(bi), bcur, acur, B)) << scur;
        js = i + 1;
    }
}

// ---------------------------------------------------------------------------
// Kernel 3: full per-class NMS for flagged classes only (coalesced scoresT
// pass, sort @1024 thr, greedy on waves 0-3). Fast classes return immediately.
// ---------------------------------------------------------------------------
__global__ __launch_bounds__(TPBF, 1) void nms_full_kernel(
    const float* __restrict__ bboxes, const float* __restrict__ scoresT,
    const float* __restrict__ conf_ptr, const float* __restrict__ nms_ptr,
    int N, const u32* __restrict__ gCtl,
    u32* __restrict__ gsi, u64* __restrict__ gkept)
{
    const int c = blockIdx.x;
    if (gCtl[1 + c] == 0u) return;

    __shared__ __align__(16) char smem[63856];
    u64*    sortbuf  = (u64*)smem;             // [0,32768)
    float4* boxesLds = (float4*)smem;          // [0,58368)
    u16*    keptR    = (u16*)(smem + 58368);
    u32*    ctl      = (u32*)(smem + 58976);
    float4* pubBox   = (float4*)(smem + 58992);
    __shared__ int cntS;

    const int tid  = threadIdx.x;
    const int lane = tid & 63;
    const int cls = c + 1;
    const float conf = *conf_ptr;
    const float nmsT = *nms_ptr;
    const u32 thetaBits = gCtl[0];

    if (tid == 0) cntS = 0;
    __syncthreads();
    const float* rowT = scoresT + (size_t)cls * N;
    const float4* rowT4 = (const float4*)rowT;
    const int N4 = N >> 2;
    for (int i4 = tid; i4 < N4; i4 += TPBF) {
        float4 s4 = rowT4[i4];
        #pragma unroll
        for (int j = 0; j < 4; j++) {
            float s = (j == 0) ? s4.x : (j == 1) ? s4.y : (j == 2) ? s4.z : s4.w;
            bool pass = (s > conf);
            u64 m = __ballot(pass);
            if (m) {
                int leader = (int)__builtin_ctzll(m);
                int base = 0;
                if (lane == leader) base = atomicAdd(&cntS, __popcll(m));
                base = __shfl(base, leader, 64);
                if (pass) {
                    int p = base + (int)__popcll(m & ((1ull << lane) - 1ull));
                    if (p < MSORT)
                        sortbuf[p] = ((u64)__float_as_uint(s) << 32) | (u32)((i4 << 2) + j);
                }
            }
        }
    }
    for (int i = (N4 << 2) + tid; i < N; i += TPBF) {
        float s = rowT[i];
        if (s > conf) {
            int p = atomicAdd(&cntS, 1);
            if (p < MSORT) sortbuf[p] = ((u64)__float_as_uint(s) << 32) | (u32)i;
        }
    }
    __syncthreads();
    int K = cntS; if (K > BOXCAP) K = BOXCAP;
    int M = 64; while (M < K) M <<= 1;
    for (int p = K + tid; p < M; p += TPBF) sortbuf[p] = 0;
    __syncthreads();
    for (int kk = 2; kk <= M; kk <<= 1) {
        for (int j = kk >> 1; j > 0; j >>= 1) {
            for (int i = tid; i < M; i += TPBF) {
                int ixj = i ^ j;
                if (ixj > i) {
                    u64 a = sortbuf[i], b = sortbuf[ixj];
                    if (((i & kk) == 0) ? (a < b) : (a > b)) { sortbuf[i] = b; sortbuf[ixj] = a; }
                }
            }
            __syncthreads();
        }
    }
    u32 myIdx[MSORT / TPBF];
    #pragma unroll
    for (int t = 0; t < MSORT / TPBF; t++) myIdx[t] = (u32)sortbuf[t * TPBF + tid];
    __syncthreads();
    u32* gsi_c = gsi + (size_t)c * BOXCAP;
    #pragma unroll
    for (int t = 0; t < MSORT / TPBF; t++) {
        int r = t * TPBF + tid;
        if (r < K) {
            u32 idx = myIdx[t];
            gsi_c[r] = idx;
            boxesLds[r] = ((const float4*)bboxes)[idx];
        }
    }
    if (tid == 0) { ctl[0] = 0; ctl[1] = 0; ctl[2] = 0; }
    __syncthreads();
    if (tid >= 256) return;

    const int wave = tid >> 6;
    const u32 tb = __float_as_uint(nmsT);
    const float Tn = __uint_as_float(tb + 1u);
    const double B = ((double)nmsT + (double)Tn) * 0.5;
    const bool geCmp = (((tb + 1u) & 1u) == 0u);
    const int smax = (K + 63) >> 6;

    int ret = geCmp ? greedy_full<true >(boxesLds, keptR, pubBox, ctl, gsi_c, rowT, thetaBits, K, smax, B, lane, wave)
                    : greedy_full<false>(boxesLds, keptR, pubBox, ctl, gsi_c, rowT, thetaBits, K, smax, B, lane, wave);
    if (ret >= 0) {
        int kept = ret; if (kept > KPC) kept = KPC;
        u64* gkept_c = gkept + (size_t)c * KPC;
        for (int p = lane; p < kept; p += 64) {
            int rank = keptR[p];
            u32 idx = gsi_c[rank];
            float sc = rowT[idx];
            u32 flat = (u32)c * (u32)N + idx;
            gkept_c[p] = ((u64)__float_as_uint(sc) << 32) | (u32)(~flat);
        }
        for (int p = kept + lane; p < KPC; p += 64) gkept_c[p] = 0;
    }
}

// ---------------------------------------------------------------------------
// Kernel 4: global top-Mout over nc*KPC kept keys (runtime-sized bitonic).
// ---------------------------------------------------------------------------
__global__ __launch_bounds__(1024) void nms_topk_kernel(
    const float* __restrict__ bboxes, const u64* __restrict__ gkept,
    int N, int nc, int Mout, float* __restrict__ out)
{
    __shared__ u32 hist[2048];
    __shared__ int selCount;
    __shared__ int bstarS;
    __shared__ u64 sel[SELCAP];

    const int tid = threadIdx.x;
    const int total = nc * KPC;

    for (int b = tid; b < 2048; b += 1024) hist[b] = 0;
    if (tid == 0) selCount = 0;
    __syncthreads();

    for (int t = tid; t < total; t += 1024) {
        u64 k = gkept[t];
        if (k) atomicAdd(&hist[scoreBin((u32)(k >> 32))], 1u);
    }
    __syncthreads();

    bstar_wave0(hist, Mout, tid, &bstarS, nullptr);
    __syncthreads();
    const int bstar = bstarS;

    for (int t = tid; t < total; t += 1024) {
        u64 k = gkept[t];
        if (k && scoreBin((u32)(k >> 32)) >= bstar) {
            int p = atomicAdd(&selCount, 1);
            if (p < SELCAP) sel[p] = k;
        }
    }
    __syncthreads();
    int cnt = selCount; if (cnt > SELCAP) cnt = SELCAP;
    int SM = 512; while (SM < cnt) SM <<= 1;       // runtime-sized (>= Mout)
    for (int p = cnt + tid; p < SM; p += 1024) sel[p] = 0;
    __syncthreads();

    for (int kk = 2; kk <= SM; kk <<= 1) {
        for (int j = kk >> 1; j > 0; j >>= 1) {
            for (int i = tid; i < SM; i += 1024) {
                int ixj = i ^ j;
                if (ixj > i) {
                    u64 a = sel[i], b = sel[ixj];
                    if (((i & kk) == 0) ? (a < b) : (a > b)) { sel[i] = b; sel[ixj] = a; }
                }
            }
            __syncthreads();
        }
    }

    for (int t = tid; t < Mout; t += 1024) {
        u64 k = (t < SM) ? sel[t] : 0;
        float px1 = 0.f, py1 = 0.f, px2 = 0.f, py2 = 0.f, ps = 0.f, plab = -1.0f;
        if (k) {
            float s  = __uint_as_float((u32)(k >> 32));
            u32 flat = ~((u32)k);
            int cc   = (int)(flat / (u32)N);
            int box  = (int)(flat - (u32)cc * (u32)N);
            float4 bb = ((const float4*)bboxes)[box];
            px1 = bb.x; py1 = bb.y; px2 = bb.z; py2 = bb.w; ps = s;
            plab = (float)(cc + 1);
        }
        out[t * 5 + 0] = px1;
        out[t * 5 + 1] = py1;
        out[t * 5 + 2] = px2;
        out[t * 5 + 3] = py2;
        out[t * 5 + 4] = ps;
        out[Mout * 5 + t] = plab;
    }
}

extern "C" void kernel_launch(void* const* d_in, const int* in_sizes, int n_in,
                              void* d_out, int out_size, void* d_ws, size_t ws_size,
                              hipStream_t stream) {
    const float* bboxes = (const float*)d_in[0];
    const float* scores = (const float*)d_in[1];
    const float* conf   = (const float*)d_in[2];
    const float* nmsT   = (const float*)d_in[3];

    const int N    = in_sizes[0] / 4;        // 5000
    const int C    = in_sizes[1] / N;        // 81
    const int nc   = C - 1;                  // 80
    const int Mout = out_size / 6;           // 300

    // ws layout: [scoresT: C*N f32][gsi][gkept][gK|g65|gPre][gCtl][gHist]
    char* wsb = (char*)d_ws;
    size_t off = 0;
    float* scoresT = (float*)(wsb + off); off += ((size_t)C * N * sizeof(float) + 255) & ~(size_t)255;
    u32* gsi   = (u32*)(wsb + off); off += (size_t)nc * BOXCAP * sizeof(u32);
    u64* gkept = (u64*)(wsb + off); off += (size_t)nc * KPC * sizeof(u64);
    u32* gK    = (u32*)(wsb + off); off += (size_t)((nc + 1) & ~1) * sizeof(u32);
    u32* g65   = (u32*)(wsb + off); off += (size_t)((nc + 1) & ~1) * sizeof(u32);
    u32* gPre  = (u32*)(wsb + off); off += (size_t)((nc + 1) & ~1) * sizeof(u32);
    u32* gCtl  = (u32*)(wsb + off); off += (size_t)((1 + nc + 1) & ~1) * sizeof(u32);
    u32* gHist = (u32*)(wsb + off); off += 2048 * sizeof(u32);

    const int ntile = (N + TBOX - 1) / TBOX;
    transpose_kernel<<<ntile, 1024, 0, stream>>>(scores, N, C, scoresT, gHist);
    nms_select_kernel<<<nc, TPB1, 0, stream>>>(bboxes, scoresT, conf, nmsT, N,
                                               gkept, gK, g65, gPre, gHist);
    nms_theta_kernel<<<1, 1024, 0, stream>>>(gHist, gK, g65, gPre, nc, Mout, gCtl);
    nms_full_kernel<<<nc, TPBF, 0, stream>>>(bboxes, scoresT, conf, nmsT, N, gCtl, gsi, gkept);
    nms_topk_kernel<<<1, 1024, 0, stream>>>(bboxes, gkept, N, nc, Mout, (float*)d_out);
}

// Round 3
// 123.138 us; speedup vs baseline: 1.0916x; 1.0115x over previous
//
#include <hip/hip_runtime.h>

typedef unsigned long long u64;
typedef unsigned int u32;
typedef unsigned short u16;

#define MSORT 4096     // fallback sort capacity (power of 2)
#define TPB1  1024     // select kernel threads
#define TPBF  1024     // finale kernel threads
#define BOXCAP 3648    // fallback: boxes staged in LDS (57 KB)
#define KCAP  3072     // select: single-pass key capacity in LDS (24 KB)
#define RSLOT_W 10     // fallback: register slots per wave
#define KPC   300      // kept recorded per class
#define SELCAP 1024
#define PREFR 64       // prefix-NMS rank budget (top-64 per class)
#define TBOX  128      // transpose: boxes per tile (128*81*4 = 41.5 KB LDS)

#define WG_SCOPE  __HIP_MEMORY_SCOPE_WORKGROUP
#define DEV_SCOPE __HIP_MEMORY_SCOPE_AGENT

__device__ __forceinline__ float boxArea(float4 b) {
    return __fmul_rn(__fsub_rn(b.z, b.x), __fsub_rn(b.w, b.y));
}

// exact numpy f32 semantics: RN32(inter/uni) > T  <=>  inter (cmp) B*uni in f64
template<bool GE>
__device__ __forceinline__ bool iou_gt(float4 a, float area_a, float4 b, float area_b, double B) {
    float ix1 = fmaxf(a.x, b.x), iy1 = fmaxf(a.y, b.y);
    float ix2 = fminf(a.z, b.z), iy2 = fminf(a.w, b.w);
    float iw  = fmaxf(__fsub_rn(ix2, ix1), 0.0f);
    float ih  = fmaxf(__fsub_rn(iy2, iy1), 0.0f);
    float inter = __fmul_rn(iw, ih);
    float uni   = __fsub_rn(__fadd_rn(area_a, area_b), inter);
    return GE ? ((double)inter >= B * (double)uni) : ((double)inter > B * (double)uni);
}

// monotone bin of a positive-float score's bit pattern (11 bits @ exp 126)
__device__ __forceinline__ int scoreBin(u32 bits) {
    int b = (int)(bits >> 12) - 0x3F000;
    return b < 0 ? 0 : (b > 2047 ? 2047 : b);
}

// ---------------------------------------------------------------------------
// Wave-0 parallel threshold-bin search (validated r1/r2, bit-identical to the
// serial two-level scan): bs = largest bin b with
// suffix_sum(hist[b..2047]) >= target (0 at edge / when total < target).
// ---------------------------------------------------------------------------
__device__ __forceinline__ void bstar_wave0(
    const u32* __restrict__ hist, int target, int tid,
    int* __restrict__ outBs, int* __restrict__ outTot)
{
    if (tid < 64) {
        int s = 0;
        #pragma unroll
        for (int b = 0; b < 32; b++)                 // rotated: 2-way banks (free)
            s += (int)hist[(tid << 5) + ((b + tid) & 31)];
        #pragma unroll
        for (int d = 1; d < 64; d <<= 1) {           // suffix-inclusive scan
            int v = __shfl_down(s, d, 64);
            if (tid + d < 64) s += v;
        }
        u64 bal = __ballot(s >= target);
        int ch  = bal ? (63 - __builtin_clzll(bal)) : -1;   // largest chunk w/ suffix>=target
        int tot = __shfl(s, 0, 64);
        int bs  = 0;
        if (ch >= 0) {
            int accAbove = (ch < 63) ? __shfl(s, ch + 1, 64) : 0;
            int h = (tid < 32) ? (int)hist[(ch << 5) + tid] : 0;
            #pragma unroll
            for (int d = 1; d < 32; d <<= 1) {
                int v = __shfl_down(h, d, 64);
                if (tid + d < 32) h += v;
            }
            u64 bal2 = __ballot((tid < 32) && (accAbove + h >= target)); // lane 0 always true
            bs = (ch << 5) + (63 - __builtin_clzll(bal2));
        }
        if (tid == 0) { *outBs = bs; if (outTot) *outTot = tot; }
    }
}

// ---------------------------------------------------------------------------
// Kernel 0: coalesced transpose scores[N][C] -> scoresT[C][N] via LDS tile.
// Block 0 also zeroes the global theta histogram + fan-in counter.
// ---------------------------------------------------------------------------
__global__ __launch_bounds__(1024) void transpose_kernel(
    const float* __restrict__ scores, int N, int C,
    float* __restrict__ scoresT, u32* __restrict__ gHist)
{
    __shared__ float tile[TBOX * 81];
    const int tid = threadIdx.x;
    const int b0  = blockIdx.x * TBOX;
    const int nb  = (N - b0 < TBOX) ? (N - b0) : TBOX;
    const int tot = nb * C;
    for (int e = tid; e < tot; e += 1024)            // coalesced read
        tile[e] = scores[(size_t)b0 * C + e];
    __syncthreads();
    if (nb == TBOX) {
        const int wtot = C << 7;
        for (int o = tid; o < wtot; o += 1024) {     // coalesced write per class row
            int cls = o >> 7, j = o & (TBOX - 1);
            scoresT[(size_t)cls * N + b0 + j] = tile[j * C + cls];
        }
    } else {
        const int wtot = C * nb;
        for (int o = tid; o < wtot; o += 1024) {
            int cls = o / nb, j = o - cls * nb;
            scoresT[(size_t)cls * N + b0 + j] = tile[j * C + cls];
        }
    }
    if (blockIdx.x == 0)
        for (int h = tid; h < 2052; h += 1024) gHist[h] = 0;   // hist + gDone pad
}

// ---------------------------------------------------------------------------
// wave-0 prefix greedy NMS over the top-R (R<=64) candidates, one per lane.
// Exact: greedy decisions for rank j depend only on kept ranks < j.
// Accumulates kept-score bins into the global theta histogram (validated r1).
// ---------------------------------------------------------------------------
template<bool GE>
__device__ __forceinline__ int prefix_nms_w0(
    const float* __restrict__ bboxes, const u64* __restrict__ sorted,
    int R, double B, int tid, int c, int N, u64* __restrict__ gkept_c,
    u32* __restrict__ gHist)
{
    u64 key = (tid < R) ? sorted[tid] : 0;
    float4 bx = make_float4(0.f, 0.f, 0.f, 0.f);
    if (tid < R) bx = ((const float4*)bboxes)[(u32)key];
    float ar = boxArea(bx);
    u64 supB = (R >= 64) ? 0ull : (~0ull << R);
    int nk = 0;
    int i = -1;
    for (;;) {
        u64 mask = (i >= 63) ? 0ull : (~0ull << (i + 1));
        u64 alive = ~supB & mask;
        if (!alive) break;
        i = (int)__builtin_ctzll(alive);
        float4 bi;
        bi.x = __shfl(bx.x, i, 64); bi.y = __shfl(bx.y, i, 64);
        bi.z = __shfl(bx.z, i, 64); bi.w = __shfl(bx.w, i, 64);
        float ai = boxArea(bi);
        if (tid == 0) {
            u64 ki = sorted[i];
            u32 flat = (u32)c * (u32)N + (u32)ki;   // top_k ties: lower flat first
            gkept_c[nk] = (ki & 0xFFFFFFFF00000000ull) | (u32)(~flat);
        }
        nk++;
        bool sup = (tid > i) && iou_gt<GE>(bi, ai, bx, ar, B);
        supB |= __ballot(sup);
    }
    if (tid < R && !((supB >> tid) & 1ull))
        atomicAdd(&gHist[scoreBin((u32)(key >> 32))], 1u);
    return nk;
}

// ---------------------------------------------------------------------------
// Kernel 1: per class — ONE coalesced float4 pass over scoresT row (ballot-
// aggregated compaction + histogram), top-65 threshold from histogram,
// compact <=256 from LDS, rank-by-count, prefix-NMS top-64.
// ---------------------------------------------------------------------------
__global__ __launch_bounds__(TPB1, 1) void nms_select_kernel(
    const float* __restrict__ bboxes, const float* __restrict__ scoresT,
    const float* __restrict__ conf_ptr, const float* __restrict__ nms_ptr,
    int N, u64* __restrict__ gkept,
    u32* __restrict__ gK, u32* __restrict__ g65, u32* __restrict__ gPre,
    u32* __restrict__ gHist)
{
    __shared__ u64 keys[KCAP];            // 24 KB
    __shared__ u32 hist[2048];            // 8 KB
    __shared__ u64 keybuf[256];
    __shared__ u64 sorted[66];
    __shared__ int cntS, ncollS, bstarS, nkS;

    const int tid  = threadIdx.x;
    const int lane = tid & 63;
    const int c    = blockIdx.x;
    const int cls  = c + 1;
    const float conf = *conf_ptr;
    const float nmsT = *nms_ptr;

    for (int b = tid; b < 2048; b += TPB1) hist[b] = 0;
    if (tid < 66) sorted[tid] = 0;
    if (tid == 0) { cntS = 0; ncollS = 0; nkS = 0; }
    __syncthreads();

    // ---- single coalesced pass: keys -> LDS + histogram (1 atomic per wave)
    const float* rowT = scoresT + (size_t)cls * N;
    const float4* rowT4 = (const float4*)rowT;
    const int N4 = N >> 2;
    for (int i4 = tid; i4 < N4; i4 += TPB1) {
        float4 s4 = rowT4[i4];
        #pragma unroll
        for (int j = 0; j < 4; j++) {
            float s = (j == 0) ? s4.x : (j == 1) ? s4.y : (j == 2) ? s4.z : s4.w;
            bool pass = (s > conf);
            u64 m = __ballot(pass);
            if (m) {
                int leader = (int)__builtin_ctzll(m);
                int base = 0;
                if (lane == leader) base = atomicAdd(&cntS, __popcll(m));
                base = __shfl(base, leader, 64);
                if (pass) {
                    int p = base + (int)__popcll(m & ((1ull << lane) - 1ull));
                    if (p < KCAP)
                        keys[p] = ((u64)__float_as_uint(s) << 32) | (u32)((i4 << 2) + j);
                    atomicAdd(&hist[scoreBin(__float_as_uint(s))], 1u);
                }
            }
        }
    }
    for (int i = (N4 << 2) + tid; i < N; i += TPB1) {   // tail (empty when N%4==0)
        float s = rowT[i];
        if (s > conf) {
            int p = atomicAdd(&cntS, 1);
            if (p < KCAP) keys[p] = ((u64)__float_as_uint(s) << 32) | (u32)i;
            atomicAdd(&hist[scoreBin(__float_as_uint(s))], 1u);
        }
    }
    __syncthreads();
    const int K = cntS;
    const bool preOv = (K > KCAP);
    const int target = K < (PREFR + 1) ? K : (PREFR + 1);

    bstar_wave0(hist, target, tid, &bstarS, nullptr);
    __syncthreads();
    const u32 tbits = (bstarS == 0) ? 0u : (((u32)bstarS + 0x3F000u) << 12);

    // ---- compact top candidates from LDS keys (no 2nd global pass)
    const int KL = K < KCAP ? K : KCAP;
    for (int p = tid; p < KL; p += TPB1) {
        u64 k = keys[p];
        if ((u32)(k >> 32) >= tbits) {
            int pos = atomicAdd(&ncollS, 1);
            if (pos < 256) keybuf[pos] = k;
        }
    }
    __syncthreads();
    const int ncoll = ncollS;
    const bool pre = preOv || (ncoll > 256);
    for (int p = ncoll + tid; p < 256; p += TPB1) keybuf[p] = 0;
    __syncthreads();

    u64* gkept_c = gkept + (size_t)c * KPC;
    if (!pre) {
        if (tid < 256) {                       // rank-by-count (keys are unique)
            u64 my = keybuf[tid];
            int rank = 0;
            for (int j = 0; j < 256; j++) rank += (keybuf[j] > my);
            if (my && rank < PREFR + 1) sorted[rank] = my;
        }
        __syncthreads();
        const u32 tb = __float_as_uint(nmsT);
        const float Tn = __uint_as_float(tb + 1u);
        const double B = ((double)nmsT + (double)Tn) * 0.5;
        const bool geCmp = (((tb + 1u) & 1u) == 0u);
        if (tid < 64) {
            int R = ncoll < PREFR ? ncoll : PREFR;
            int nk = geCmp ? prefix_nms_w0<true >(bboxes, sorted, R, B, tid, c, N, gkept_c, gHist)
                           : prefix_nms_w0<false>(bboxes, sorted, R, B, tid, c, N, gkept_c, gHist);
            if (tid == 0) nkS = nk;
        }
        __syncthreads();
        for (int p = nkS + tid; p < KPC; p += TPB1) gkept_c[p] = 0;
    } else {
        for (int p = tid; p < KPC; p += TPB1) gkept_c[p] = 0;
    }
    if (tid == 0) {
        gK[c]   = (u32)K;
        g65[c]  = pre ? 0xFFFFFFFFu : ((ncoll >= PREFR + 1) ? (u32)(sorted[PREFR] >> 32) : 0u);
        gPre[c] = pre ? 1u : 0u;
    }
}

// ---------------------------------------------------------------------------
// Fallback greedy (lazy producer/consumer, 4 waves) with stop at theta.
// ---------------------------------------------------------------------------
template<bool GE>
__device__ __forceinline__ u64 sweep_own(
    float4 bi, float area_i, const float4 (&breg)[RSLOT_W],
    const float (&areaj)[RSLOT_W], const float4* __restrict__ boxesLds,
    int base, int nslots, int lane, double B)
{
    u64 ns = 0;
    #pragma unroll
    for (int t = 0; t < RSLOT_W; t++)
        ns |= ((u64)iou_gt<GE>(bi, area_i, breg[t], areaj[t], B)) << (base + t);
    for (int t = RSLOT_W; t < nslots; t++) {
        float4 bj = boxesLds[((base + t) << 6) | lane];
        ns |= ((u64)iou_gt<GE>(bi, area_i, bj, boxArea(bj), B)) << (base + t);
    }
    return ns;
}

template<bool GE>
__device__ __forceinline__ int greedy_full(
    const float4* __restrict__ boxesLds, u16* __restrict__ keptR,
    float4* __restrict__ pubBox, u32* __restrict__ ctl,
    const u32* __restrict__ gsi_c, const float* __restrict__ rowT,
    u32 thetaBits,
    int K, int smax, double B, int lane, int wave)
{
    const int SW   = (smax + 3) >> 2;
    const int base = (wave * SW < smax) ? wave * SW : smax;
    const int end  = (base + SW < smax) ? base + SW : smax;
    const int nslots = end - base;

    float4 breg[RSLOT_W];
    float  areaj[RSLOT_W];
    #pragma unroll
    for (int t = 0; t < RSLOT_W; t++) {
        float4 b = boxesLds[((base + t) << 6) | lane];
        breg[t] = b;
        areaj[t] = boxArea(b);
    }

    u64 sup;
    {
        int t = (lane < K) ? ((K - lane + 63) >> 6) : 0;
        sup = (t >= 64) ? 0ull : (~0ull << t);
    }

    u32 seen = 0;
    if (wave != 0) {
        for (;;) {
            u32 d  = __hip_atomic_load(&ctl[2], __ATOMIC_ACQUIRE, WG_SCOPE);
            u32 cn = __hip_atomic_load(&ctl[0], __ATOMIC_ACQUIRE, WG_SCOPE);
            bool prog = (seen < cn);
            while (seen < cn) {
                float4 bi = pubBox[seen]; seen++;
                sup |= sweep_own<GE>(bi, boxArea(bi), breg, areaj, boxesLds, base, nslots, lane, B);
            }
            if (d) return -1;
            u32 aw = __hip_atomic_load(&ctl[1], __ATOMIC_ACQUIRE, WG_SCOPE);
            if (aw == (u32)wave) {
                u32 cn2 = __hip_atomic_load(&ctl[0], __ATOMIC_ACQUIRE, WG_SCOPE);
                while (seen < cn2) {
                    float4 bi = pubBox[seen]; seen++;
                    sup |= sweep_own<GE>(bi, boxArea(bi), breg, areaj, boxesLds, base, nslots, lane, B);
                }
                break;
            }
            if (!prog) __builtin_amdgcn_s_sleep(1);
        }
    }

    u32 nk = seen;
    const u32 seen0 = seen;
    int scur = base - 1;
    float4 bcur = make_float4(0.f, 0.f, 0.f, 0.f);
    float  acur = 0.f;
    int js = base << 6;

    for (;;) {
        int s = js >> 6;
        while (s > scur) {
            scur++;
            if (scur < end) {
                bcur = boxesLds[(scur << 6) | lane];
                acur = boxArea(bcur);
                u64 bit = 0;
                for (u32 k = seen0; k < nk; k++) {
                    float4 bk = pubBox[k];
                    bit |= ((u64)iou_gt<GE>(bk, boxArea(bk), bcur, acur, B));
                }
                sup |= bit << scur;
            }
        }
        if (scur >= end) {
            if (wave == 3) {
                if (lane == 0) __hip_atomic_store(&ctl[2], 1u, __ATOMIC_RELEASE, WG_SCOPE);
                return (int)nk;
            }
            if (lane == 0) __hip_atomic_store(&ctl[1], (u32)(wave + 1), __ATOMIC_RELEASE, WG_SCOPE);
            return -1;
        }
        u64 bal = __ballot((int)(((~sup) >> scur) & 1ull)) & (~0ull << (js & 63));
        if (bal == 0) { js = (scur + 1) << 6; continue; }
        int i = (scur << 6) + (int)__builtin_ctzll(bal);

        if (thetaBits) {
            u32 idx = gsi_c[i];
            float sc = rowT[idx];                    // 20 KB row: L1/L2-hit
            if (__float_as_uint(sc) < thetaBits) {
                if (lane == 0) __hip_atomic_store(&ctl[2], 1u, __ATOMIC_RELEASE, WG_SCOPE);
                return (int)nk;
            }
        }
        float4 bi = boxesLds[i];
        if (lane == 0) { pubBox[nk] = bi; keptR[nk] = (u16)i; }
        nk++;
        if (nk >= KPC) {
            if (lane == 0) {
                __hip_atomic_store(&ctl[0], nk, __ATOMIC_RELEASE, WG_SCOPE);
                __hip_atomic_store(&ctl[2], 1u, __ATOMIC_RELEASE, WG_SCOPE);
            }
            return (int)nk;
        }
        if (lane == 0) __hip_atomic_store(&ctl[0], nk, __ATOMIC_RELEASE, WG_SCOPE);
        sup |= ((u64)iou_gt<GE>(bi, boxArea(bi), bcur, acur, B)) << scur;
        js = i + 1;
    }
}

// ---------------------------------------------------------------------------
// Kernel 2 (fused theta + full + topk):
//  - every block loads the 8 KB kept-histogram, computes theta + own needFull
//    (removes the single-block theta dispatch; all cross-block inputs are
//    kernel-boundary-fenced from select);
//  - flagged blocks run full NMS (RELEASE arrival — wbl2 only when gkept was
//    rewritten); unflagged blocks arrive RELAXED (no cache writeback);
//  - last arriver ACQUIRE-syncs once and runs global top-Mout in reused LDS.
// ---------------------------------------------------------------------------
__global__ __launch_bounds__(TPBF, 1) void nms_finale_kernel(
    const float* __restrict__ bboxes, const float* __restrict__ scoresT,
    const float* __restrict__ conf_ptr, const float* __restrict__ nms_ptr,
    int N, const u32* __restrict__ gHist,
    const u32* __restrict__ gK, const u32* __restrict__ g65, const u32* __restrict__ gPre,
    u32* __restrict__ gsi, u64* __restrict__ gkept,
    int Mout, float* __restrict__ out, u32* __restrict__ gDone)
{
    __shared__ __align__(16) char smem[63856];
    __shared__ int cntS, lastS, selCountS, bs4S, thBs, thTot;

    const int c    = blockIdx.x;
    const int tid  = threadIdx.x;
    const int lane = tid & 63;

    // ---- phase T: per-block theta from the 8 KB global kept-histogram
    u32* histT = (u32*)smem;
    for (int b = tid; b < 2048; b += TPBF) histT[b] = gHist[b];
    __syncthreads();
    bstar_wave0(histT, Mout, tid, &thBs, &thTot);
    __syncthreads();
    const u32 thetaBits = (thTot >= Mout && thBs > 0) ? (((u32)thBs + 0x3F000u) << 12) : 0u;
    u32 need = gPre[c];
    if (gK[c] > PREFR && g65[c] >= thetaBits) need = 1u;   // theta==0 -> always
    __syncthreads();                                       // histT dead; smem reusable

    // ---- phase F: full per-class NMS for flagged classes only
    if (need) {
        u64*    sortbuf  = (u64*)smem;             // [0,32768)
        float4* boxesLds = (float4*)smem;          // [0,58368)
        u16*    keptR    = (u16*)(smem + 58368);
        u32*    ctl      = (u32*)(smem + 58976);
        float4* pubBox   = (float4*)(smem + 58992);

        const int cls = c + 1;
        const float conf = *conf_ptr;
        const float nmsT = *nms_ptr;

        if (tid == 0) cntS = 0;
        __syncthreads();
        const float* rowT = scoresT + (size_t)cls * N;
        const float4* rowT4 = (const float4*)rowT;
        const int N4 = N >> 2;
        for (int i4 = tid; i4 < N4; i4 += TPBF) {
            float4 s4 = rowT4[i4];
            #pragma unroll
            for (int j = 0; j < 4; j++) {
                float s = (j == 0) ? s4.x : (j == 1) ? s4.y : (j == 2) ? s4.z : s4.w;
                bool pass = (s > conf);
                u64 m = __ballot(pass);
                if (m) {
                    int leader = (int)__builtin_ctzll(m);
                    int base = 0;
                    if (lane == leader) base = atomicAdd(&cntS, __popcll(m));
                    base = __shfl(base, leader, 64);
                    if (pass) {
                        int p = base + (int)__popcll(m & ((1ull << lane) - 1ull));
                        if (p < MSORT)
                            sortbuf[p] = ((u64)__float_as_uint(s) << 32) | (u32)((i4 << 2) + j);
                    }
                }
            }
        }
        for (int i = (N4 << 2) + tid; i < N; i += TPBF) {
            float s = rowT[i];
            if (s > conf) {
                int p = atomicAdd(&cntS, 1);
                if (p < MSORT) sortbuf[p] = ((u64)__float_as_uint(s) << 32) | (u32)i;
            }
        }
        __syncthreads();
        int K = cntS; if (K > BOXCAP) K = BOXCAP;
        int M = 64; while (M < K) M <<= 1;
        for (int p = K + tid; p < M; p += TPBF) sortbuf[p] = 0;
        __syncthreads();
        for (int kk = 2; kk <= M; kk <<= 1) {
            for (int j = kk >> 1; j > 0; j >>= 1) {
                for (int i = tid; i < M; i += TPBF) {
                    int ixj = i ^ j;
                    if (ixj > i) {
                        u64 a = sortbuf[i], b = sortbuf[ixj];
                        if (((i & kk) == 0) ? (a < b) : (a > b)) { sortbuf[i] = b; sortbuf[ixj] = a; }
                    }
                }
                __syncthreads();
            }
        }
        u32 myIdx[MSORT / TPBF];
        #pragma unroll
        for (int t = 0; t < MSORT / TPBF; t++) myIdx[t] = (u32)sortbuf[t * TPBF + tid];
        __syncthreads();
        u32* gsi_c = gsi + (size_t)c * BOXCAP;
        #pragma unroll
        for (int t = 0; t < MSORT / TPBF; t++) {
            int r = t * TPBF + tid;
            if (r < K) {
                u32 idx = myIdx[t];
                gsi_c[r] = idx;
                boxesLds[r] = ((const float4*)bboxes)[idx];
            }
        }
        if (tid == 0) { ctl[0] = 0; ctl[1] = 0; ctl[2] = 0; }
        __syncthreads();

        if (tid < 256) {
            const int wave = tid >> 6;
            const u32 tb = __float_as_uint(nmsT);
            const float Tn = __uint_as_float(tb + 1u);
            const double B = ((double)nmsT + (double)Tn) * 0.5;
            const bool geCmp = (((tb + 1u) & 1u) == 0u);
            const int smax = (K + 63) >> 6;

            int ret = geCmp ? greedy_full<true >(boxesLds, keptR, pubBox, ctl, gsi_c, rowT, thetaBits, K, smax, B, lane, wave)
                            : greedy_full<false>(boxesLds, keptR, pubBox, ctl, gsi_c, rowT, thetaBits, K, smax, B, lane, wave);
            if (ret >= 0) {
                int kept = ret; if (kept > KPC) kept = KPC;
                u64* gkept_c = gkept + (size_t)c * KPC;
                for (int p = lane; p < kept; p += 64) {
                    int rank = keptR[p];
                    u32 idx = gsi_c[rank];
                    float sc = rowT[idx];
                    u32 flat = (u32)c * (u32)N + idx;
                    gkept_c[p] = ((u64)__float_as_uint(sc) << 32) | (u32)(~flat);
                }
                for (int p = kept + lane; p < KPC; p += 64) gkept_c[p] = 0;
            }
        }
    }

    // ---- fan-in: RELEASE only if this block rewrote gkept; RELAXED otherwise
    __syncthreads();
    if (tid == 0) {
        u32 v = need ? __hip_atomic_fetch_add(gDone, 1u, __ATOMIC_RELEASE, DEV_SCOPE)
                     : __hip_atomic_fetch_add(gDone, 1u, __ATOMIC_RELAXED, DEV_SCOPE);
        lastS = (v == (u32)(gridDim.x - 1)) ? 1 : 0;
    }
    __syncthreads();
    if (!lastS) return;
    if (tid == 0)                       // single acquire (cache-inv, no writeback)
        __hip_atomic_fetch_add(gDone, 0u, __ATOMIC_ACQUIRE, DEV_SCOPE);
    __syncthreads();

    // ---- phase K: global top-Mout over nc*KPC kept keys (reused LDS)
    u64* sel   = (u64*)smem;                    // 8 KB
    u32* hist4 = (u32*)(smem + 8192);           // 8 KB
    const int total = (int)gridDim.x * KPC;

    for (int b = tid; b < 2048; b += TPBF) hist4[b] = 0;
    if (tid == 0) selCountS = 0;
    __syncthreads();

    for (int t = tid; t < total; t += TPBF) {
        u64 k = gkept[t];
        if (k) atomicAdd(&hist4[scoreBin((u32)(k >> 32))], 1u);
    }
    __syncthreads();

    bstar_wave0(hist4, Mout, tid, &bs4S, nullptr);
    __syncthreads();
    const int bstar = bs4S;

    for (int t = tid; t < total; t += TPBF) {
        u64 k = gkept[t];
        if (k && scoreBin((u32)(k >> 32)) >= bstar) {
            int p = atomicAdd(&selCountS, 1);
            if (p < SELCAP) sel[p] = k;
        }
    }
    __syncthreads();
    int cnt = selCountS; if (cnt > SELCAP) cnt = SELCAP;
    int SM = 512; while (SM < cnt) SM <<= 1;       // runtime-sized (>= Mout)
    for (int p = cnt + tid; p < SM; p += TPBF) sel[p] = 0;
    __syncthreads();

    for (int kk = 2; kk <= SM; kk <<= 1) {
        for (int j = kk >> 1; j > 0; j >>= 1) {
            for (int i = tid; i < SM; i += TPBF) {
                int ixj = i ^ j;
                if (ixj > i) {
                    u64 a = sel[i], b = sel[ixj];
                    if (((i & kk) == 0) ? (a < b) : (a > b)) { sel[i] = b; sel[ixj] = a; }
                }
            }
            __syncthreads();
        }
    }

    for (int t = tid; t < Mout; t += TPBF) {
        u64 k = (t < SM) ? sel[t] : 0;
        float px1 = 0.f, py1 = 0.f, px2 = 0.f, py2 = 0.f, ps = 0.f, plab = -1.0f;
        if (k) {
            float s  = __uint_as_float((u32)(k >> 32));
            u32 flat = ~((u32)k);
            int cc   = (int)(flat / (u32)N);
            int box  = (int)(flat - (u32)cc * (u32)N);
            float4 bb = ((const float4*)bboxes)[box];
            px1 = bb.x; py1 = bb.y; px2 = bb.z; py2 = bb.w; ps = s;
            plab = (float)(cc + 1);
        }
        out[t * 5 + 0] = px1;
        out[t * 5 + 1] = py1;
        out[t * 5 + 2] = px2;
        out[t * 5 + 3] = py2;
        out[t * 5 + 4] = ps;
        out[Mout * 5 + t] = plab;
    }
}

extern "C" void kernel_launch(void* const* d_in, const int* in_sizes, int n_in,
                              void* d_out, int out_size, void* d_ws, size_t ws_size,
                              hipStream_t stream) {
    const float* bboxes = (const float*)d_in[0];
    const float* scores = (const float*)d_in[1];
    const float* conf   = (const float*)d_in[2];
    const float* nmsT   = (const float*)d_in[3];

    const int N    = in_sizes[0] / 4;        // 5000
    const int C    = in_sizes[1] / N;        // 81
    const int nc   = C - 1;                  // 80
    const int Mout = out_size / 6;           // 300

    // ws layout: [scoresT: C*N f32][gsi][gkept][gK|g65|gPre][gHist(2048)+gDone]
    char* wsb = (char*)d_ws;
    size_t off = 0;
    float* scoresT = (float*)(wsb + off); off += ((size_t)C * N * sizeof(float) + 255) & ~(size_t)255;
    u32* gsi   = (u32*)(wsb + off); off += (size_t)nc * BOXCAP * sizeof(u32);
    u64* gkept = (u64*)(wsb + off); off += (size_t)nc * KPC * sizeof(u64);
    u32* gK    = (u32*)(wsb + off); off += (size_t)((nc + 1) & ~1) * sizeof(u32);
    u32* g65   = (u32*)(wsb + off); off += (size_t)((nc + 1) & ~1) * sizeof(u32);
    u32* gPre  = (u32*)(wsb + off); off += (size_t)((nc + 1) & ~1) * sizeof(u32);
    u32* gHist = (u32*)(wsb + off); off += 2052 * sizeof(u32);   // hist + gDone + pad
    u32* gDone = gHist + 2048;

    const int ntile = (N + TBOX - 1) / TBOX;
    transpose_kernel<<<ntile, 1024, 0, stream>>>(scores, N, C, scoresT, gHist);
    nms_select_kernel<<<nc, TPB1, 0, stream>>>(bboxes, scoresT, conf, nmsT, N,
                                               gkept, gK, g65, gPre, gHist);
    nms_finale_kernel<<<nc, TPBF, 0, stream>>>(bboxes, scoresT, conf, nmsT, N,
                                               gHist, gK, g65, gPre, gsi, gkept,
                                               Mout, (float*)d_out, gDone);
}

// Round 5
// 113.554 us; speedup vs baseline: 1.1837x; 1.0844x over previous
//
#include <hip/hip_runtime.h>

typedef unsigned long long u64;
typedef unsigned int u32;
typedef unsigned short u16;

#define MSORT 4096     // fallback sort capacity (power of 2)
#define TPB1  1024     // select kernel threads
#define TPBF  1024     // finale kernel threads
#define BOXCAP 3648    // fallback: boxes staged in LDS (57 KB)
#define KCAP  3072     // select: single-pass key capacity in LDS (24 KB)
#define RSLOT_W 10     // fallback: register slots per wave
#define KPC   300      // kept recorded per class
#define SELCAP 1024
#define PREFR 64       // prefix-NMS rank budget (top-64 per class)
#define TBOX  128      // transpose: boxes per tile (128*81*4 = 41.5 KB LDS)

#define WG_SCOPE  __HIP_MEMORY_SCOPE_WORKGROUP
#define DEV_SCOPE __HIP_MEMORY_SCOPE_AGENT

__device__ __forceinline__ float boxArea(float4 b) {
    return __fmul_rn(__fsub_rn(b.z, b.x), __fsub_rn(b.w, b.y));
}

// exact numpy f32 semantics: RN32(inter/uni) > T  <=>  inter (cmp) B*uni in f64
template<bool GE>
__device__ __forceinline__ bool iou_gt(float4 a, float area_a, float4 b, float area_b, double B) {
    float ix1 = fmaxf(a.x, b.x), iy1 = fmaxf(a.y, b.y);
    float ix2 = fminf(a.z, b.z), iy2 = fminf(a.w, b.w);
    float iw  = fmaxf(__fsub_rn(ix2, ix1), 0.0f);
    float ih  = fmaxf(__fsub_rn(iy2, iy1), 0.0f);
    float inter = __fmul_rn(iw, ih);
    float uni   = __fsub_rn(__fadd_rn(area_a, area_b), inter);
    return GE ? ((double)inter >= B * (double)uni) : ((double)inter > B * (double)uni);
}

// monotone bin of a positive-float score's bit pattern (11 bits @ exp 126)
__device__ __forceinline__ int scoreBin(u32 bits) {
    int b = (int)(bits >> 12) - 0x3F000;
    return b < 0 ? 0 : (b > 2047 ? 2047 : b);
}

// ---------------------------------------------------------------------------
// Wave-0 parallel threshold-bin search (validated r1-r3, bit-identical to the
// serial two-level scan): bs = largest bin b with
// suffix_sum(hist[b..2047]) >= target (0 at edge / when total < target).
// ---------------------------------------------------------------------------
__device__ __forceinline__ void bstar_wave0(
    const u32* __restrict__ hist, int target, int tid,
    int* __restrict__ outBs, int* __restrict__ outTot)
{
    if (tid < 64) {
        int s = 0;
        #pragma unroll
        for (int b = 0; b < 32; b++)                 // rotated: 2-way banks (free)
            s += (int)hist[(tid << 5) + ((b + tid) & 31)];
        #pragma unroll
        for (int d = 1; d < 64; d <<= 1) {           // suffix-inclusive scan
            int v = __shfl_down(s, d, 64);
            if (tid + d < 64) s += v;
        }
        u64 bal = __ballot(s >= target);
        int ch  = bal ? (63 - __builtin_clzll(bal)) : -1;   // largest chunk w/ suffix>=target
        int tot = __shfl(s, 0, 64);
        int bs  = 0;
        if (ch >= 0) {
            int accAbove = (ch < 63) ? __shfl(s, ch + 1, 64) : 0;
            int h = (tid < 32) ? (int)hist[(ch << 5) + tid] : 0;
            #pragma unroll
            for (int d = 1; d < 32; d <<= 1) {
                int v = __shfl_down(h, d, 64);
                if (tid + d < 32) h += v;
            }
            u64 bal2 = __ballot((tid < 32) && (accAbove + h >= target)); // lane 0 always true
            bs = (ch << 5) + (63 - __builtin_clzll(bal2));
        }
        if (tid == 0) { *outBs = bs; if (outTot) *outTot = tot; }
    }
}

// ---------------------------------------------------------------------------
// Kernel 0: coalesced transpose scores[N][C] -> scoresT[C][N] via LDS tile.
// Block 0 also zeroes gHist + fan-in/rerun counters.
// ---------------------------------------------------------------------------
__global__ __launch_bounds__(1024) void transpose_kernel(
    const float* __restrict__ scores, int N, int C,
    float* __restrict__ scoresT, u32* __restrict__ gHist)
{
    __shared__ float tile[TBOX * 81];
    const int tid = threadIdx.x;
    const int b0  = blockIdx.x * TBOX;
    const int nb  = (N - b0 < TBOX) ? (N - b0) : TBOX;
    const int tot = nb * C;
    for (int e = tid; e < tot; e += 1024)            // coalesced read
        tile[e] = scores[(size_t)b0 * C + e];
    __syncthreads();
    if (nb == TBOX) {
        const int wtot = C << 7;
        for (int o = tid; o < wtot; o += 1024) {     // coalesced write per class row
            int cls = o >> 7, j = o & (TBOX - 1);
            scoresT[(size_t)cls * N + b0 + j] = tile[j * C + cls];
        }
    } else {
        const int wtot = C * nb;
        for (int o = tid; o < wtot; o += 1024) {
            int cls = o / nb, j = o - cls * nb;
            scoresT[(size_t)cls * N + b0 + j] = tile[j * C + cls];
        }
    }
    if (blockIdx.x == 0)                 // hist(2048) + {gDone, gRerun, pad}
        for (int h = tid; h < 2052; h += 1024) gHist[h] = 0;
}

// ---------------------------------------------------------------------------
// wave-0 prefix greedy NMS over the top-R (R<=64) candidates, one per lane.
// Exact: greedy decisions for rank j depend only on kept ranks < j.
// Accumulates kept-score bins into the global theta histogram (validated r1).
// ---------------------------------------------------------------------------
template<bool GE>
__device__ __forceinline__ int prefix_nms_w0(
    const float* __restrict__ bboxes, const u64* __restrict__ sorted,
    int R, double B, int tid, int c, int N, u64* __restrict__ gkept_c,
    u32* __restrict__ gHist)
{
    u64 key = (tid < R) ? sorted[tid] : 0;
    float4 bx = make_float4(0.f, 0.f, 0.f, 0.f);
    if (tid < R) bx = ((const float4*)bboxes)[(u32)key];
    float ar = boxArea(bx);
    u64 supB = (R >= 64) ? 0ull : (~0ull << R);
    int nk = 0;
    int i = -1;
    for (;;) {
        u64 mask = (i >= 63) ? 0ull : (~0ull << (i + 1));
        u64 alive = ~supB & mask;
        if (!alive) break;
        i = (int)__builtin_ctzll(alive);
        float4 bi;
        bi.x = __shfl(bx.x, i, 64); bi.y = __shfl(bx.y, i, 64);
        bi.z = __shfl(bx.z, i, 64); bi.w = __shfl(bx.w, i, 64);
        float ai = boxArea(bi);
        if (tid == 0) {
            u64 ki = sorted[i];
            u32 flat = (u32)c * (u32)N + (u32)ki;   // top_k ties: lower flat first
            gkept_c[nk] = (ki & 0xFFFFFFFF00000000ull) | (u32)(~flat);
        }
        nk++;
        bool sup = (tid > i) && iou_gt<GE>(bi, ai, bx, ar, B);
        supB |= __ballot(sup);
    }
    if (tid < R && !((supB >> tid) & 1ull))
        atomicAdd(&gHist[scoreBin((u32)(key >> 32))], 1u);
    return nk;
}

// ---------------------------------------------------------------------------
// Kernel 1: per class — ONE coalesced float4 pass over scoresT row (ballot-
// aggregated compaction + histogram), top-65 threshold from histogram,
// compact <=256 from LDS, rank-by-count, prefix-NMS top-64.
// ---------------------------------------------------------------------------
__global__ __launch_bounds__(TPB1, 1) void nms_select_kernel(
    const float* __restrict__ bboxes, const float* __restrict__ scoresT,
    const float* __restrict__ conf_ptr, const float* __restrict__ nms_ptr,
    int N, u64* __restrict__ gkept,
    u32* __restrict__ gK, u32* __restrict__ g65, u32* __restrict__ gPre,
    u32* __restrict__ gHist)
{
    __shared__ u64 keys[KCAP];            // 24 KB
    __shared__ u32 hist[2048];            // 8 KB
    __shared__ u64 keybuf[256];
    __shared__ u64 sorted[66];
    __shared__ int cntS, ncollS, bstarS, nkS;

    const int tid  = threadIdx.x;
    const int lane = tid & 63;
    const int c    = blockIdx.x;
    const int cls  = c + 1;
    const float conf = *conf_ptr;
    const float nmsT = *nms_ptr;

    for (int b = tid; b < 2048; b += TPB1) hist[b] = 0;
    if (tid < 66) sorted[tid] = 0;
    if (tid == 0) { cntS = 0; ncollS = 0; nkS = 0; }
    __syncthreads();

    // ---- single coalesced pass: keys -> LDS + histogram (1 atomic per wave)
    const float* rowT = scoresT + (size_t)cls * N;
    const float4* rowT4 = (const float4*)rowT;
    const int N4 = N >> 2;
    for (int i4 = tid; i4 < N4; i4 += TPB1) {
        float4 s4 = rowT4[i4];
        #pragma unroll
        for (int j = 0; j < 4; j++) {
            float s = (j == 0) ? s4.x : (j == 1) ? s4.y : (j == 2) ? s4.z : s4.w;
            bool pass = (s > conf);
            u64 m = __ballot(pass);
            if (m) {
                int leader = (int)__builtin_ctzll(m);
                int base = 0;
                if (lane == leader) base = atomicAdd(&cntS, __popcll(m));
                base = __shfl(base, leader, 64);
                if (pass) {
                    int p = base + (int)__popcll(m & ((1ull << lane) - 1ull));
                    if (p < KCAP)
                        keys[p] = ((u64)__float_as_uint(s) << 32) | (u32)((i4 << 2) + j);
                    atomicAdd(&hist[scoreBin(__float_as_uint(s))], 1u);
                }
            }
        }
    }
    for (int i = (N4 << 2) + tid; i < N; i += TPB1) {   // tail (empty when N%4==0)
        float s = rowT[i];
        if (s > conf) {
            int p = atomicAdd(&cntS, 1);
            if (p < KCAP) keys[p] = ((u64)__float_as_uint(s) << 32) | (u32)i;
            atomicAdd(&hist[scoreBin(__float_as_uint(s))], 1u);
        }
    }
    __syncthreads();
    const int K = cntS;
    const bool preOv = (K > KCAP);
    const int target = K < (PREFR + 1) ? K : (PREFR + 1);

    bstar_wave0(hist, target, tid, &bstarS, nullptr);
    __syncthreads();
    const u32 tbits = (bstarS == 0) ? 0u : (((u32)bstarS + 0x3F000u) << 12);

    // ---- compact top candidates from LDS keys (ballot-aggregated)
    const int KL = K < KCAP ? K : KCAP;
    for (int p = tid; p < KL; p += TPB1) {
        u64 k = keys[p];
        bool pass = ((u32)(k >> 32) >= tbits);
        u64 m = __ballot(pass);
        if (m) {
            int leader = (int)__builtin_ctzll(m);
            int base = 0;
            if (lane == leader) base = atomicAdd(&ncollS, (int)__popcll(m));
            base = __shfl(base, leader, 64);
            if (pass) {
                int pos = base + (int)__popcll(m & ((1ull << lane) - 1ull));
                if (pos < 256) keybuf[pos] = k;
            }
        }
    }
    __syncthreads();
    const int ncoll = ncollS;
    const bool pre = preOv || (ncoll > 256);
    for (int p = ncoll + tid; p < 256; p += TPB1) keybuf[p] = 0;
    __syncthreads();

    u64* gkept_c = gkept + (size_t)c * KPC;
    if (!pre) {
        if (tid < 256) {                       // rank-by-count (keys are unique)
            u64 my = keybuf[tid];
            int rank = 0;
            for (int j = 0; j < 256; j++) rank += (keybuf[j] > my);
            if (my && rank < PREFR + 1) sorted[rank] = my;
        }
        __syncthreads();
        const u32 tb = __float_as_uint(nmsT);
        const float Tn = __uint_as_float(tb + 1u);
        const double B = ((double)nmsT + (double)Tn) * 0.5;
        const bool geCmp = (((tb + 1u) & 1u) == 0u);
        if (tid < 64) {
            int R = ncoll < PREFR ? ncoll : PREFR;
            int nk = geCmp ? prefix_nms_w0<true >(bboxes, sorted, R, B, tid, c, N, gkept_c, gHist)
                           : prefix_nms_w0<false>(bboxes, sorted, R, B, tid, c, N, gkept_c, gHist);
            if (tid == 0) nkS = nk;
        }
        __syncthreads();
        for (int p = nkS + tid; p < KPC; p += TPB1) gkept_c[p] = 0;
    } else {
        for (int p = tid; p < KPC; p += TPB1) gkept_c[p] = 0;
    }
    if (tid == 0) {
        gK[c]   = (u32)K;
        g65[c]  = pre ? 0xFFFFFFFFu : ((ncoll >= PREFR + 1) ? (u32)(sorted[PREFR] >> 32) : 0u);
        gPre[c] = pre ? 1u : 0u;
    }
}

// ---------------------------------------------------------------------------
// Fallback greedy (lazy producer/consumer, 4 waves) with stop at theta.
// ---------------------------------------------------------------------------
template<bool GE>
__device__ __forceinline__ u64 sweep_own(
    float4 bi, float area_i, const float4 (&breg)[RSLOT_W],
    const float (&areaj)[RSLOT_W], const float4* __restrict__ boxesLds,
    int base, int nslots, int lane, double B)
{
    u64 ns = 0;
    #pragma unroll
    for (int t = 0; t < RSLOT_W; t++)
        ns |= ((u64)iou_gt<GE>(bi, area_i, breg[t], areaj[t], B)) << (base + t);
    for (int t = RSLOT_W; t < nslots; t++) {
        float4 bj = boxesLds[((base + t) << 6) | lane];
        ns |= ((u64)iou_gt<GE>(bi, area_i, bj, boxArea(bj), B)) << (base + t);
    }
    return ns;
}

template<bool GE>
__device__ __forceinline__ int greedy_full(
    const float4* __restrict__ boxesLds, u16* __restrict__ keptR,
    float4* __restrict__ pubBox, u32* __restrict__ ctl,
    const u32* __restrict__ gsi_c, const float* __restrict__ rowT,
    u32 thetaBits,
    int K, int smax, double B, int lane, int wave)
{
    const int SW   = (smax + 3) >> 2;
    const int base = (wave * SW < smax) ? wave * SW : smax;
    const int end  = (base + SW < smax) ? base + SW : smax;
    const int nslots = end - base;

    float4 breg[RSLOT_W];
    float  areaj[RSLOT_W];
    #pragma unroll
    for (int t = 0; t < RSLOT_W; t++) {
        float4 b = boxesLds[((base + t) << 6) | lane];
        breg[t] = b;
        areaj[t] = boxArea(b);
    }

    u64 sup;
    {
        int t = (lane < K) ? ((K - lane + 63) >> 6) : 0;
        sup = (t >= 64) ? 0ull : (~0ull << t);
    }

    u32 seen = 0;
    if (wave != 0) {
        for (;;) {
            u32 d  = __hip_atomic_load(&ctl[2], __ATOMIC_ACQUIRE, WG_SCOPE);
            u32 cn = __hip_atomic_load(&ctl[0], __ATOMIC_ACQUIRE, WG_SCOPE);
            bool prog = (seen < cn);
            while (seen < cn) {
                float4 bi = pubBox[seen]; seen++;
                sup |= sweep_own<GE>(bi, boxArea(bi), breg, areaj, boxesLds, base, nslots, lane, B);
            }
            if (d) return -1;
            u32 aw = __hip_atomic_load(&ctl[1], __ATOMIC_ACQUIRE, WG_SCOPE);
            if (aw == (u32)wave) {
                u32 cn2 = __hip_atomic_load(&ctl[0], __ATOMIC_ACQUIRE, WG_SCOPE);
                while (seen < cn2) {
                    float4 bi = pubBox[seen]; seen++;
                    sup |= sweep_own<GE>(bi, boxArea(bi), breg, areaj, boxesLds, base, nslots, lane, B);
                }
                break;
            }
            if (!prog) __builtin_amdgcn_s_sleep(1);
        }
    }

    u32 nk = seen;
    const u32 seen0 = seen;
    int scur = base - 1;
    float4 bcur = make_float4(0.f, 0.f, 0.f, 0.f);
    float  acur = 0.f;
    int js = base << 6;

    for (;;) {
        int s = js >> 6;
        while (s > scur) {
            scur++;
            if (scur < end) {
                bcur = boxesLds[(scur << 6) | lane];
                acur = boxArea(bcur);
                u64 bit = 0;
                for (u32 k = seen0; k < nk; k++) {
                    float4 bk = pubBox[k];
                    bit |= ((u64)iou_gt<GE>(bk, boxArea(bk), bcur, acur, B));
                }
                sup |= bit << scur;
            }
        }
        if (scur >= end) {
            if (wave == 3) {
                if (lane == 0) __hip_atomic_store(&ctl[2], 1u, __ATOMIC_RELEASE, WG_SCOPE);
                return (int)nk;
            }
            if (lane == 0) __hip_atomic_store(&ctl[1], (u32)(wave + 1), __ATOMIC_RELEASE, WG_SCOPE);
            return -1;
        }
        u64 bal = __ballot((int)(((~sup) >> scur) & 1ull)) & (~0ull << (js & 63));
        if (bal == 0) { js = (scur + 1) << 6; continue; }
        int i = (scur << 6) + (int)__builtin_ctzll(bal);

        if (thetaBits) {
            u32 idx = gsi_c[i];
            float sc = rowT[idx];                    // 20 KB row: L1/L2-hit
            if (__float_as_uint(sc) < thetaBits) {
                if (lane == 0) __hip_atomic_store(&ctl[2], 1u, __ATOMIC_RELEASE, WG_SCOPE);
                return (int)nk;
            }
        }
        float4 bi = boxesLds[i];
        if (lane == 0) { pubBox[nk] = bi; keptR[nk] = (u16)i; }
        nk++;
        if (nk >= KPC) {
            if (lane == 0) {
                __hip_atomic_store(&ctl[0], nk, __ATOMIC_RELEASE, WG_SCOPE);
                __hip_atomic_store(&ctl[2], 1u, __ATOMIC_RELEASE, WG_SCOPE);
            }
            return (int)nk;
        }
        if (lane == 0) __hip_atomic_store(&ctl[0], nk, __ATOMIC_RELEASE, WG_SCOPE);
        sup |= ((u64)iou_gt<GE>(bi, boxArea(bi), bcur, acur, B)) << scur;
        js = i + 1;
    }
}

// ---------------------------------------------------------------------------
// Kernel 2 (fused theta + full + topk):
//  phase T: every block computes theta + own needFull from immutable gHist;
//  phase F: flagged blocks rerun full NMS (bump gRerun, RELEASE arrival);
//           unflagged blocks arrive RELAXED (no L2 writeback);
//  last arriver (ACQUIRE once): fast path (gRerun==0) reuses thBs==bstar —
//  ONE ballot-compacted pass over gkept into LDS + rank-by-count sort
//  (no histogram pass, no 45-round bitonic). Slow path (reruns) recomputes
//  bstar from a histogram pass, then compacts — original R3 semantics.
//  All cross-block data the last block reads (gkept) is either
//  kernel-boundary-fenced (select) or RELEASE-published (rerun blocks).
// ---------------------------------------------------------------------------
__global__ __launch_bounds__(TPBF, 1) void nms_finale_kernel(
    const float* __restrict__ bboxes, const float* __restrict__ scoresT,
    const float* __restrict__ conf_ptr, const float* __restrict__ nms_ptr,
    int N, const u32* __restrict__ gHist,
    const u32* __restrict__ gK, const u32* __restrict__ g65, const u32* __restrict__ gPre,
    u32* __restrict__ gsi, u64* __restrict__ gkept,
    int Mout, float* __restrict__ out,
    u32* __restrict__ gDone, u32* __restrict__ gRerun)
{
    __shared__ __align__(16) char smem[63856];
    __shared__ int cntS, lastS, selCountS, bs4S, thBs, thTot, nRerunS;

    const int c    = blockIdx.x;
    const int tid  = threadIdx.x;
    const int lane = tid & 63;

    // ---- phase T: per-block theta from the immutable 8 KB kept-histogram
    u32* histT = (u32*)smem;
    for (int b = tid; b < 2048; b += TPBF) histT[b] = gHist[b];
    __syncthreads();
    bstar_wave0(histT, Mout, tid, &thBs, &thTot);
    __syncthreads();
    const int  thBsL = thBs;
    const u32 thetaBits = (thTot >= Mout && thBsL > 0) ? (((u32)thBsL + 0x3F000u) << 12) : 0u;
    u32 need = gPre[c];
    if (gK[c] > PREFR && g65[c] >= thetaBits) need = 1u;   // theta==0 -> always
    __syncthreads();                                       // histT dead; smem reusable

    u64* gkept_c = gkept + (size_t)c * KPC;

    // ---- phase F: full per-class NMS for flagged classes only
    if (need) {
        if (tid == 0) atomicAdd(gRerun, 1u);   // published by RELEASE arrival below

        u64*    sortbuf  = (u64*)smem;             // [0,32768)
        float4* boxesLds = (float4*)smem;          // [0,58368)
        u16*    keptR    = (u16*)(smem + 58368);
        u32*    ctl      = (u32*)(smem + 58976);
        float4* pubBox   = (float4*)(smem + 58992);

        const int cls = c + 1;
        const float conf = *conf_ptr;
        const float nmsT = *nms_ptr;

        if (tid == 0) cntS = 0;
        __syncthreads();
        const float* rowT = scoresT + (size_t)cls * N;
        const float4* rowT4 = (const float4*)rowT;
        const int N4 = N >> 2;
        for (int i4 = tid; i4 < N4; i4 += TPBF) {
            float4 s4 = rowT4[i4];
            #pragma unroll
            for (int j = 0; j < 4; j++) {
                float s = (j == 0) ? s4.x : (j == 1) ? s4.y : (j == 2) ? s4.z : s4.w;
                bool pass = (s > conf);
                u64 m = __ballot(pass);
                if (m) {
                    int leader = (int)__builtin_ctzll(m);
                    int base = 0;
                    if (lane == leader) base = atomicAdd(&cntS, __popcll(m));
                    base = __shfl(base, leader, 64);
                    if (pass) {
                        int p = base + (int)__popcll(m & ((1ull << lane) - 1ull));
                        if (p < MSORT)
                            sortbuf[p] = ((u64)__float_as_uint(s) << 32) | (u32)((i4 << 2) + j);
                    }
                }
            }
        }
        for (int i = (N4 << 2) + tid; i < N; i += TPBF) {
            float s = rowT[i];
            if (s > conf) {
                int p = atomicAdd(&cntS, 1);
                if (p < MSORT) sortbuf[p] = ((u64)__float_as_uint(s) << 32) | (u32)i;
            }
        }
        __syncthreads();
        int K = cntS; if (K > BOXCAP) K = BOXCAP;
        int M = 64; while (M < K) M <<= 1;
        for (int p = K + tid; p < M; p += TPBF) sortbuf[p] = 0;
        __syncthreads();
        for (int kk = 2; kk <= M; kk <<= 1) {
            for (int j = kk >> 1; j > 0; j >>= 1) {
                for (int i = tid; i < M; i += TPBF) {
                    int ixj = i ^ j;
                    if (ixj > i) {
                        u64 a = sortbuf[i], b = sortbuf[ixj];
                        if (((i & kk) == 0) ? (a < b) : (a > b)) { sortbuf[i] = b; sortbuf[ixj] = a; }
                    }
                }
                __syncthreads();
            }
        }
        u32 myIdx[MSORT / TPBF];
        #pragma unroll
        for (int t = 0; t < MSORT / TPBF; t++) myIdx[t] = (u32)sortbuf[t * TPBF + tid];
        __syncthreads();
        u32* gsi_c = gsi + (size_t)c * BOXCAP;
        #pragma unroll
        for (int t = 0; t < MSORT / TPBF; t++) {
            int r = t * TPBF + tid;
            if (r < K) {
                u32 idx = myIdx[t];
                gsi_c[r] = idx;
                boxesLds[r] = ((const float4*)bboxes)[idx];
            }
        }
        if (tid == 0) { ctl[0] = 0; ctl[1] = 0; ctl[2] = 0; }
        __syncthreads();

        if (tid < 256) {
            const int wave = tid >> 6;
            const u32 tb = __float_as_uint(nmsT);
            const float Tn = __uint_as_float(tb + 1u);
            const double B = ((double)nmsT + (double)Tn) * 0.5;
            const bool geCmp = (((tb + 1u) & 1u) == 0u);
            const int smax = (K + 63) >> 6;

            int ret = geCmp ? greedy_full<true >(boxesLds, keptR, pubBox, ctl, gsi_c, rowT, thetaBits, K, smax, B, lane, wave)
                            : greedy_full<false>(boxesLds, keptR, pubBox, ctl, gsi_c, rowT, thetaBits, K, smax, B, lane, wave);
            if (ret >= 0) {
                int kept = ret; if (kept > KPC) kept = KPC;
                for (int p = lane; p < kept; p += 64) {
                    int rank = keptR[p];
                    u32 idx = gsi_c[rank];
                    float sc = rowT[idx];
                    u32 flat = (u32)c * (u32)N + idx;
                    gkept_c[p] = ((u64)__float_as_uint(sc) << 32) | (u32)(~flat);
                }
                for (int p = kept + lane; p < KPC; p += 64) gkept_c[p] = 0;
            }
        }
    }

    // ---- fan-in: RELEASE only if this block rewrote gkept; RELAXED otherwise
    __syncthreads();
    if (tid == 0) {
        u32 v = need ? __hip_atomic_fetch_add(gDone, 1u, __ATOMIC_RELEASE, DEV_SCOPE)
                     : __hip_atomic_fetch_add(gDone, 1u, __ATOMIC_RELAXED, DEV_SCOPE);
        lastS = (v == (u32)(gridDim.x - 1)) ? 1 : 0;
    }
    __syncthreads();
    if (!lastS) return;
    if (tid == 0) {                     // single acquire (cache-inv, no writeback)
        __hip_atomic_fetch_add(gDone, 0u, __ATOMIC_ACQUIRE, DEV_SCOPE);
        nRerunS = (int)__hip_atomic_load(gRerun, __ATOMIC_ACQUIRE, DEV_SCOPE);
    }
    __syncthreads();

    // ---- last block: assemble candidate set from gkept
    u64* selL  = (u64*)smem;                    // 8 KB
    u32* hist4 = (u32*)(smem + 8192);           // 8 KB
    const int total = (int)gridDim.x * KPC;
    int bstar;

    if (nRerunS == 0) {
        // gHist is exactly the histogram of gkept -> thBs == bstar (r3/r4 phase T)
        bstar = thBsL;
    } else {
        // reruns mutated gkept: recompute bstar from a histogram pass
        for (int b = tid; b < 2048; b += TPBF) hist4[b] = 0;
        __syncthreads();
        for (int t = tid; t < total; t += TPBF) {
            u64 k = gkept[t];
            if (k) atomicAdd(&hist4[scoreBin((u32)(k >> 32))], 1u);
        }
        __syncthreads();
        bstar_wave0(hist4, Mout, tid, &bs4S, nullptr);
        __syncthreads();
        bstar = bs4S;
    }

    // ONE ballot-compacted pass: keys with bin >= bstar -> selL
    if (tid == 0) selCountS = 0;
    __syncthreads();
    for (int t = tid; t < total; t += TPBF) {
        u64 k = gkept[t];
        bool pass = (k != 0) && (scoreBin((u32)(k >> 32)) >= bstar);
        u64 m = __ballot(pass);
        if (m) {
            int leader = (int)__builtin_ctzll(m);
            int base = 0;
            if (lane == leader) base = atomicAdd(&selCountS, (int)__popcll(m));
            base = __shfl(base, leader, 64);
            if (pass) {
                int p = base + (int)__popcll(m & ((1ull << lane) - 1ull));
                if (p < SELCAP) selL[p] = k;
            }
        }
    }
    __syncthreads();
    int cnt = selCountS; if (cnt > SELCAP) cnt = SELCAP;

    // ---- rank-by-count sort (keys unique) + output
    for (int t = tid; t < Mout; t += TPBF) {        // prefill empty slots
        out[t * 5 + 0] = 0.f; out[t * 5 + 1] = 0.f; out[t * 5 + 2] = 0.f;
        out[t * 5 + 3] = 0.f; out[t * 5 + 4] = 0.f;
        out[Mout * 5 + t] = -1.0f;
    }
    __syncthreads();
    if (tid < cnt) {
        u64 my = selL[tid];
        int rank = 0;
        for (int j = 0; j < cnt; j++) rank += (selL[j] > my);   // broadcast reads
        if (rank < Mout) {
            float s  = __uint_as_float((u32)(my >> 32));
            u32 flat = ~((u32)my);
            int cc   = (int)(flat / (u32)N);
            int box  = (int)(flat - (u32)cc * (u32)N);
            float4 bb = ((const float4*)bboxes)[box];
            out[rank * 5 + 0] = bb.x;
            out[rank * 5 + 1] = bb.y;
            out[rank * 5 + 2] = bb.z;
            out[rank * 5 + 3] = bb.w;
            out[rank * 5 + 4] = s;
            out[Mout * 5 + rank] = (float)(cc + 1);
        }
    }
}

extern "C" void kernel_launch(void* const* d_in, const int* in_sizes, int n_in,
                              void* d_out, int out_size, void* d_ws, size_t ws_size,
                              hipStream_t stream) {
    const float* bboxes = (const float*)d_in[0];
    const float* scores = (const float*)d_in[1];
    const float* conf   = (const float*)d_in[2];
    const float* nmsT   = (const float*)d_in[3];

    const int N    = in_sizes[0] / 4;        // 5000
    const int C    = in_sizes[1] / N;        // 81
    const int nc   = C - 1;                  // 80
    const int Mout = out_size / 6;           // 300

    // ws layout: [scoresT][gsi][gkept][gK|g65|gPre][gHist(2048)|gDone|gRerun|pad]
    char* wsb = (char*)d_ws;
    size_t off = 0;
    float* scoresT = (float*)(wsb + off); off += ((size_t)C * N * sizeof(float) + 255) & ~(size_t)255;
    u32* gsi   = (u32*)(wsb + off); off += (size_t)nc * BOXCAP * sizeof(u32);
    u64* gkept = (u64*)(wsb + off); off += (size_t)nc * KPC * sizeof(u64);
    u32* gK    = (u32*)(wsb + off); off += (size_t)((nc + 1) & ~1) * sizeof(u32);
    u32* g65   = (u32*)(wsb + off); off += (size_t)((nc + 1) & ~1) * sizeof(u32);
    u32* gPre  = (u32*)(wsb + off); off += (size_t)((nc + 1) & ~1) * sizeof(u32);
    u32* gHist = (u32*)(wsb + off); off += 2052 * sizeof(u32);
    u32* gDone  = gHist + 2048;
    u32* gRerun = gHist + 2049;

    const int ntile = (N + TBOX - 1) / TBOX;
    transpose_kernel<<<ntile, 1024, 0, stream>>>(scores, N, C, scoresT, gHist);
    nms_select_kernel<<<nc, TPB1, 0, stream>>>(bboxes, scoresT, conf, nmsT, N,
                                               gkept, gK, g65, gPre, gHist);
    nms_finale_kernel<<<nc, TPBF, 0, stream>>>(bboxes, scoresT, conf, nmsT, N,
                                               gHist, gK, g65, gPre, gsi, gkept,
                                               Mout, (float*)d_out, gDone, gRerun);
}

// Round 6
// 111.291 us; speedup vs baseline: 1.2078x; 1.0203x over previous
//
#include <hip/hip_runtime.h>

typedef unsigned long long u64;
typedef unsigned int u32;
typedef unsigned short u16;

#define MSORT 4096     // fallback sort capacity (power of 2)
#define TPB1  1024     // select kernel threads
#define TPBF  1024     // finale kernel threads
#define BOXCAP 3648    // fallback: boxes staged in LDS (57 KB)
#define KCAP  3072     // select: single-pass key capacity in LDS (24 KB)
#define RSLOT_W 10     // fallback: register slots per wave
#define KPC   300      // kept recorded per class
#define SELCAP 1024
#define PREFR 64       // prefix-NMS rank budget (top-64 per class)
#define TBOX  128      // transpose: boxes per tile (128*81*4 = 41.5 KB LDS)

#define WG_SCOPE  __HIP_MEMORY_SCOPE_WORKGROUP
#define DEV_SCOPE __HIP_MEMORY_SCOPE_AGENT

__device__ __forceinline__ float boxArea(float4 b) {
    return __fmul_rn(__fsub_rn(b.z, b.x), __fsub_rn(b.w, b.y));
}

// exact numpy f32 semantics: RN32(inter/uni) > T  <=>  inter (cmp) B*uni in f64
template<bool GE>
__device__ __forceinline__ bool iou_gt(float4 a, float area_a, float4 b, float area_b, double B) {
    float ix1 = fmaxf(a.x, b.x), iy1 = fmaxf(a.y, b.y);
    float ix2 = fminf(a.z, b.z), iy2 = fminf(a.w, b.w);
    float iw  = fmaxf(__fsub_rn(ix2, ix1), 0.0f);
    float ih  = fmaxf(__fsub_rn(iy2, iy1), 0.0f);
    float inter = __fmul_rn(iw, ih);
    float uni   = __fsub_rn(__fadd_rn(area_a, area_b), inter);
    return GE ? ((double)inter >= B * (double)uni) : ((double)inter > B * (double)uni);
}

// monotone bin of a positive-float score's bit pattern (11 bits @ exp 126)
__device__ __forceinline__ int scoreBin(u32 bits) {
    int b = (int)(bits >> 12) - 0x3F000;
    return b < 0 ? 0 : (b > 2047 ? 2047 : b);
}

// ---------------------------------------------------------------------------
// Wave-0 parallel threshold-bin search (validated r1-r5, bit-identical to the
// serial two-level scan): bs = largest bin b with
// suffix_sum(hist[b..2047]) >= target (0 at edge / when total < target).
// ---------------------------------------------------------------------------
__device__ __forceinline__ void bstar_wave0(
    const u32* __restrict__ hist, int target, int tid,
    int* __restrict__ outBs, int* __restrict__ outTot)
{
    if (tid < 64) {
        int s = 0;
        #pragma unroll
        for (int b = 0; b < 32; b++)                 // rotated: 2-way banks (free)
            s += (int)hist[(tid << 5) + ((b + tid) & 31)];
        #pragma unroll
        for (int d = 1; d < 64; d <<= 1) {           // suffix-inclusive scan
            int v = __shfl_down(s, d, 64);
            if (tid + d < 64) s += v;
        }
        u64 bal = __ballot(s >= target);
        int ch  = bal ? (63 - __builtin_clzll(bal)) : -1;   // largest chunk w/ suffix>=target
        int tot = __shfl(s, 0, 64);
        int bs  = 0;
        if (ch >= 0) {
            int accAbove = (ch < 63) ? __shfl(s, ch + 1, 64) : 0;
            int h = (tid < 32) ? (int)hist[(ch << 5) + tid] : 0;
            #pragma unroll
            for (int d = 1; d < 32; d <<= 1) {
                int v = __shfl_down(h, d, 64);
                if (tid + d < 32) h += v;
            }
            u64 bal2 = __ballot((tid < 32) && (accAbove + h >= target)); // lane 0 always true
            bs = (ch << 5) + (63 - __builtin_clzll(bal2));
        }
        if (tid == 0) { *outBs = bs; if (outTot) *outTot = tot; }
    }
}

// ---------------------------------------------------------------------------
// Kernel 0: coalesced transpose scores[N][C] -> scoresT[C][N] via LDS tile.
// Block 0 also zeroes gHist + fan-in/rerun counters.
// ---------------------------------------------------------------------------
__global__ __launch_bounds__(1024) void transpose_kernel(
    const float* __restrict__ scores, int N, int C,
    float* __restrict__ scoresT, u32* __restrict__ gHist)
{
    __shared__ float tile[TBOX * 81];
    const int tid = threadIdx.x;
    const int b0  = blockIdx.x * TBOX;
    const int nb  = (N - b0 < TBOX) ? (N - b0) : TBOX;
    const int tot = nb * C;
    for (int e = tid; e < tot; e += 1024)            // coalesced read
        tile[e] = scores[(size_t)b0 * C + e];
    __syncthreads();
    if (nb == TBOX) {
        const int wtot = C << 7;
        for (int o = tid; o < wtot; o += 1024) {     // coalesced write per class row
            int cls = o >> 7, j = o & (TBOX - 1);
            scoresT[(size_t)cls * N + b0 + j] = tile[j * C + cls];
        }
    } else {
        const int wtot = C * nb;
        for (int o = tid; o < wtot; o += 1024) {
            int cls = o / nb, j = o - cls * nb;
            scoresT[(size_t)cls * N + b0 + j] = tile[j * C + cls];
        }
    }
    if (blockIdx.x == 0)                 // hist(2048) + {gDone, gRerun, pad}
        for (int h = tid; h < 2052; h += 1024) gHist[h] = 0;
}

// ---------------------------------------------------------------------------
// wave-0 prefix greedy NMS over the top-R (R<=64) candidates, one per lane.
// Exact: greedy decisions for rank j depend only on kept ranks < j.
// Accumulates kept-score bins into the global theta histogram (validated r1).
// ---------------------------------------------------------------------------
template<bool GE>
__device__ __forceinline__ int prefix_nms_w0(
    const float* __restrict__ bboxes, const u64* __restrict__ sorted,
    int R, double B, int tid, int c, int N, u64* __restrict__ gkept_c,
    u32* __restrict__ gHist)
{
    u64 key = (tid < R) ? sorted[tid] : 0;
    float4 bx = make_float4(0.f, 0.f, 0.f, 0.f);
    if (tid < R) bx = ((const float4*)bboxes)[(u32)key];
    float ar = boxArea(bx);
    u64 supB = (R >= 64) ? 0ull : (~0ull << R);
    int nk = 0;
    int i = -1;
    for (;;) {
        u64 mask = (i >= 63) ? 0ull : (~0ull << (i + 1));
        u64 alive = ~supB & mask;
        if (!alive) break;
        i = (int)__builtin_ctzll(alive);
        float4 bi;
        bi.x = __shfl(bx.x, i, 64); bi.y = __shfl(bx.y, i, 64);
        bi.z = __shfl(bx.z, i, 64); bi.w = __shfl(bx.w, i, 64);
        float ai = boxArea(bi);
        if (tid == 0) {
            u64 ki = sorted[i];
            u32 flat = (u32)c * (u32)N + (u32)ki;   // top_k ties: lower flat first
            gkept_c[nk] = (ki & 0xFFFFFFFF00000000ull) | (u32)(~flat);
        }
        nk++;
        bool sup = (tid > i) && iou_gt<GE>(bi, ai, bx, ar, B);
        supB |= __ballot(sup);
    }
    if (tid < R && !((supB >> tid) & 1ull))
        atomicAdd(&gHist[scoreBin((u32)(key >> 32))], 1u);
    return nk;
}

// ---------------------------------------------------------------------------
// Kernel 1: per class — ONE coalesced float4 pass over scoresT row (ballot-
// aggregated compaction + histogram), top-65 threshold from histogram,
// compact <=256 from LDS, rank-by-count, prefix-NMS top-64.
// Writes gNk[c] = kept count; gkept slots beyond the count are NEVER read
// (count-gated consumers) so no zero-fill is needed.
// ---------------------------------------------------------------------------
__global__ __launch_bounds__(TPB1, 1) void nms_select_kernel(
    const float* __restrict__ bboxes, const float* __restrict__ scoresT,
    const float* __restrict__ conf_ptr, const float* __restrict__ nms_ptr,
    int N, u64* __restrict__ gkept,
    u32* __restrict__ gK, u32* __restrict__ g65, u32* __restrict__ gPre,
    u32* __restrict__ gHist, u32* __restrict__ gNk)
{
    __shared__ u64 keys[KCAP];            // 24 KB
    __shared__ u32 hist[2048];            // 8 KB
    __shared__ u64 keybuf[256];
    __shared__ u64 sorted[66];
    __shared__ int cntS, ncollS, bstarS, nkS;

    const int tid  = threadIdx.x;
    const int lane = tid & 63;
    const int c    = blockIdx.x;
    const int cls  = c + 1;
    const float conf = *conf_ptr;
    const float nmsT = *nms_ptr;

    for (int b = tid; b < 2048; b += TPB1) hist[b] = 0;
    if (tid < 66) sorted[tid] = 0;
    if (tid == 0) { cntS = 0; ncollS = 0; nkS = 0; }
    __syncthreads();

    // ---- single coalesced pass: keys -> LDS + histogram (1 atomic per wave)
    const float* rowT = scoresT + (size_t)cls * N;
    const float4* rowT4 = (const float4*)rowT;
    const int N4 = N >> 2;
    for (int i4 = tid; i4 < N4; i4 += TPB1) {
        float4 s4 = rowT4[i4];
        #pragma unroll
        for (int j = 0; j < 4; j++) {
            float s = (j == 0) ? s4.x : (j == 1) ? s4.y : (j == 2) ? s4.z : s4.w;
            bool pass = (s > conf);
            u64 m = __ballot(pass);
            if (m) {
                int leader = (int)__builtin_ctzll(m);
                int base = 0;
                if (lane == leader) base = atomicAdd(&cntS, __popcll(m));
                base = __shfl(base, leader, 64);
                if (pass) {
                    int p = base + (int)__popcll(m & ((1ull << lane) - 1ull));
                    if (p < KCAP)
                        keys[p] = ((u64)__float_as_uint(s) << 32) | (u32)((i4 << 2) + j);
                    atomicAdd(&hist[scoreBin(__float_as_uint(s))], 1u);
                }
            }
        }
    }
    for (int i = (N4 << 2) + tid; i < N; i += TPB1) {   // tail (empty when N%4==0)
        float s = rowT[i];
        if (s > conf) {
            int p = atomicAdd(&cntS, 1);
            if (p < KCAP) keys[p] = ((u64)__float_as_uint(s) << 32) | (u32)i;
            atomicAdd(&hist[scoreBin(__float_as_uint(s))], 1u);
        }
    }
    __syncthreads();
    const int K = cntS;
    const bool preOv = (K > KCAP);
    const int target = K < (PREFR + 1) ? K : (PREFR + 1);

    bstar_wave0(hist, target, tid, &bstarS, nullptr);
    __syncthreads();
    const u32 tbits = (bstarS == 0) ? 0u : (((u32)bstarS + 0x3F000u) << 12);

    // ---- compact top candidates from LDS keys (ballot-aggregated)
    const int KL = K < KCAP ? K : KCAP;
    for (int p = tid; p < KL; p += TPB1) {
        u64 k = keys[p];
        bool pass = ((u32)(k >> 32) >= tbits);
        u64 m = __ballot(pass);
        if (m) {
            int leader = (int)__builtin_ctzll(m);
            int base = 0;
            if (lane == leader) base = atomicAdd(&ncollS, (int)__popcll(m));
            base = __shfl(base, leader, 64);
            if (pass) {
                int pos = base + (int)__popcll(m & ((1ull << lane) - 1ull));
                if (pos < 256) keybuf[pos] = k;
            }
        }
    }
    __syncthreads();
    const int ncoll = ncollS;
    const bool pre = preOv || (ncoll > 256);
    for (int p = ncoll + tid; p < 256; p += TPB1) keybuf[p] = 0;
    __syncthreads();

    u64* gkept_c = gkept + (size_t)c * KPC;
    if (!pre) {
        if (tid < 256) {                       // rank-by-count (keys are unique)
            u64 my = keybuf[tid];
            int rank = 0;
            for (int j = 0; j < 256; j++) rank += (keybuf[j] > my);
            if (my && rank < PREFR + 1) sorted[rank] = my;
        }
        __syncthreads();
        const u32 tb = __float_as_uint(nmsT);
        const float Tn = __uint_as_float(tb + 1u);
        const double B = ((double)nmsT + (double)Tn) * 0.5;
        const bool geCmp = (((tb + 1u) & 1u) == 0u);
        if (tid < 64) {
            int R = ncoll < PREFR ? ncoll : PREFR;
            int nk = geCmp ? prefix_nms_w0<true >(bboxes, sorted, R, B, tid, c, N, gkept_c, gHist)
                           : prefix_nms_w0<false>(bboxes, sorted, R, B, tid, c, N, gkept_c, gHist);
            if (tid == 0) nkS = nk;
        }
        __syncthreads();
    }
    if (tid == 0) {
        gK[c]   = (u32)K;
        g65[c]  = pre ? 0xFFFFFFFFu : ((ncoll >= PREFR + 1) ? (u32)(sorted[PREFR] >> 32) : 0u);
        gPre[c] = pre ? 1u : 0u;
        gNk[c]  = pre ? 0u : (u32)nkS;
    }
}

// ---------------------------------------------------------------------------
// Fallback greedy (lazy producer/consumer, 4 waves) with stop at theta.
// ---------------------------------------------------------------------------
template<bool GE>
__device__ __forceinline__ u64 sweep_own(
    float4 bi, float area_i, const float4 (&breg)[RSLOT_W],
    const float (&areaj)[RSLOT_W], const float4* __restrict__ boxesLds,
    int base, int nslots, int lane, double B)
{
    u64 ns = 0;
    #pragma unroll
    for (int t = 0; t < RSLOT_W; t++)
        ns |= ((u64)iou_gt<GE>(bi, area_i, breg[t], areaj[t], B)) << (base + t);
    for (int t = RSLOT_W; t < nslots; t++) {
        float4 bj = boxesLds[((base + t) << 6) | lane];
        ns |= ((u64)iou_gt<GE>(bi, area_i, bj, boxArea(bj), B)) << (base + t);
    }
    return ns;
}

template<bool GE>
__device__ __forceinline__ int greedy_full(
    const float4* __restrict__ boxesLds, u16* __restrict__ keptR,
    float4* __restrict__ pubBox, u32* __restrict__ ctl,
    const u32* __restrict__ gsi_c, const float* __restrict__ rowT,
    u32 thetaBits,
    int K, int smax, double B, int lane, int wave)
{
    const int SW   = (smax + 3) >> 2;
    const int base = (wave * SW < smax) ? wave * SW : smax;
    const int end  = (base + SW < smax) ? base + SW : smax;
    const int nslots = end - base;

    float4 breg[RSLOT_W];
    float  areaj[RSLOT_W];
    #pragma unroll
    for (int t = 0; t < RSLOT_W; t++) {
        float4 b = boxesLds[((base + t) << 6) | lane];
        breg[t] = b;
        areaj[t] = boxArea(b);
    }

    u64 sup;
    {
        int t = (lane < K) ? ((K - lane + 63) >> 6) : 0;
        sup = (t >= 64) ? 0ull : (~0ull << t);
    }

    u32 seen = 0;
    if (wave != 0) {
        for (;;) {
            u32 d  = __hip_atomic_load(&ctl[2], __ATOMIC_ACQUIRE, WG_SCOPE);
            u32 cn = __hip_atomic_load(&ctl[0], __ATOMIC_ACQUIRE, WG_SCOPE);
            bool prog = (seen < cn);
            while (seen < cn) {
                float4 bi = pubBox[seen]; seen++;
                sup |= sweep_own<GE>(bi, boxArea(bi), breg, areaj, boxesLds, base, nslots, lane, B);
            }
            if (d) return -1;
            u32 aw = __hip_atomic_load(&ctl[1], __ATOMIC_ACQUIRE, WG_SCOPE);
            if (aw == (u32)wave) {
                u32 cn2 = __hip_atomic_load(&ctl[0], __ATOMIC_ACQUIRE, WG_SCOPE);
                while (seen < cn2) {
                    float4 bi = pubBox[seen]; seen++;
                    sup |= sweep_own<GE>(bi, boxArea(bi), breg, areaj, boxesLds, base, nslots, lane, B);
                }
                break;
            }
            if (!prog) __builtin_amdgcn_s_sleep(1);
        }
    }

    u32 nk = seen;
    const u32 seen0 = seen;
    int scur = base - 1;
    float4 bcur = make_float4(0.f, 0.f, 0.f, 0.f);
    float  acur = 0.f;
    int js = base << 6;

    for (;;) {
        int s = js >> 6;
        while (s > scur) {
            scur++;
            if (scur < end) {
                bcur = boxesLds[(scur << 6) | lane];
                acur = boxArea(bcur);
                u64 bit = 0;
                for (u32 k = seen0; k < nk; k++) {
                    float4 bk = pubBox[k];
                    bit |= ((u64)iou_gt<GE>(bk, boxArea(bk), bcur, acur, B));
                }
                sup |= bit << scur;
            }
        }
        if (scur >= end) {
            if (wave == 3) {
                if (lane == 0) __hip_atomic_store(&ctl[2], 1u, __ATOMIC_RELEASE, WG_SCOPE);
                return (int)nk;
            }
            if (lane == 0) __hip_atomic_store(&ctl[1], (u32)(wave + 1), __ATOMIC_RELEASE, WG_SCOPE);
            return -1;
        }
        u64 bal = __ballot((int)(((~sup) >> scur) & 1ull)) & (~0ull << (js & 63));
        if (bal == 0) { js = (scur + 1) << 6; continue; }
        int i = (scur << 6) + (int)__builtin_ctzll(bal);

        if (thetaBits) {
            u32 idx = gsi_c[i];
            float sc = rowT[idx];                    // 20 KB row: L1/L2-hit
            if (__float_as_uint(sc) < thetaBits) {
                if (lane == 0) __hip_atomic_store(&ctl[2], 1u, __ATOMIC_RELEASE, WG_SCOPE);
                return (int)nk;
            }
        }
        float4 bi = boxesLds[i];
        if (lane == 0) { pubBox[nk] = bi; keptR[nk] = (u16)i; }
        nk++;
        if (nk >= KPC) {
            if (lane == 0) {
                __hip_atomic_store(&ctl[0], nk, __ATOMIC_RELEASE, WG_SCOPE);
                __hip_atomic_store(&ctl[2], 1u, __ATOMIC_RELEASE, WG_SCOPE);
            }
            return (int)nk;
        }
        if (lane == 0) __hip_atomic_store(&ctl[0], nk, __ATOMIC_RELEASE, WG_SCOPE);
        sup |= ((u64)iou_gt<GE>(bi, boxArea(bi), bcur, acur, B)) << scur;
        js = i + 1;
    }
}

// ---------------------------------------------------------------------------
// Kernel 2 (fused theta + full + topk), count-gated tail:
//  phase T: every block computes theta + own needFull from immutable gHist;
//  phase F: flagged blocks rerun full NMS, update gNk[c], RELEASE arrival;
//           unflagged blocks arrive RELAXED (no L2 writeback);
//  last arriver (ACQUIRE once): loads the 80 gNk counts, then reads ONLY the
//  valid gkept slots (~26 KB, not 192 KB). Fast path (gRerun==0) reuses
//  thBs==bstar; slow path recomputes bstar from the count-gated keys.
//  All data the last block reads is kernel-boundary-fenced (select) or
//  RELEASE-published (rerun blocks) — the r3/r5-validated pattern.
// ---------------------------------------------------------------------------
__global__ __launch_bounds__(TPBF, 1) void nms_finale_kernel(
    const float* __restrict__ bboxes, const float* __restrict__ scoresT,
    const float* __restrict__ conf_ptr, const float* __restrict__ nms_ptr,
    int N, const u32* __restrict__ gHist,
    const u32* __restrict__ gK, const u32* __restrict__ g65, const u32* __restrict__ gPre,
    u32* __restrict__ gsi, u64* __restrict__ gkept,
    int Mout, float* __restrict__ out,
    u32* __restrict__ gDone, u32* __restrict__ gRerun, u32* __restrict__ gNk)
{
    __shared__ __align__(16) char smem[63856];
    __shared__ int cntS, lastS, selCountS, bs4S, thBs, thTot, nRerunS;

    const int c    = blockIdx.x;
    const int tid  = threadIdx.x;
    const int lane = tid & 63;

    // ---- phase T: per-block theta from the immutable 8 KB kept-histogram
    u32* histT = (u32*)smem;
    for (int b = tid; b < 2048; b += TPBF) histT[b] = gHist[b];
    __syncthreads();
    bstar_wave0(histT, Mout, tid, &thBs, &thTot);
    __syncthreads();
    const int  thBsL = thBs;
    const u32 thetaBits = (thTot >= Mout && thBsL > 0) ? (((u32)thBsL + 0x3F000u) << 12) : 0u;
    u32 need = gPre[c];
    if (gK[c] > PREFR && g65[c] >= thetaBits) need = 1u;   // theta==0 -> always
    __syncthreads();                                       // histT dead; smem reusable

    u64* gkept_c = gkept + (size_t)c * KPC;

    // ---- phase F: full per-class NMS for flagged classes only
    if (need) {
        if (tid == 0) atomicAdd(gRerun, 1u);   // published by RELEASE arrival below

        u64*    sortbuf  = (u64*)smem;             // [0,32768)
        float4* boxesLds = (float4*)smem;          // [0,58368)
        u16*    keptR    = (u16*)(smem + 58368);
        u32*    ctl      = (u32*)(smem + 58976);
        float4* pubBox   = (float4*)(smem + 58992);

        const int cls = c + 1;
        const float conf = *conf_ptr;
        const float nmsT = *nms_ptr;

        if (tid == 0) cntS = 0;
        __syncthreads();
        const float* rowT = scoresT + (size_t)cls * N;
        const float4* rowT4 = (const float4*)rowT;
        const int N4 = N >> 2;
        for (int i4 = tid; i4 < N4; i4 += TPBF) {
            float4 s4 = rowT4[i4];
            #pragma unroll
            for (int j = 0; j < 4; j++) {
                float s = (j == 0) ? s4.x : (j == 1) ? s4.y : (j == 2) ? s4.z : s4.w;
                bool pass = (s > conf);
                u64 m = __ballot(pass);
                if (m) {
                    int leader = (int)__builtin_ctzll(m);
                    int base = 0;
                    if (lane == leader) base = atomicAdd(&cntS, __popcll(m));
                    base = __shfl(base, leader, 64);
                    if (pass) {
                        int p = base + (int)__popcll(m & ((1ull << lane) - 1ull));
                        if (p < MSORT)
                            sortbuf[p] = ((u64)__float_as_uint(s) << 32) | (u32)((i4 << 2) + j);
                    }
                }
            }
        }
        for (int i = (N4 << 2) + tid; i < N; i += TPBF) {
            float s = rowT[i];
            if (s > conf) {
                int p = atomicAdd(&cntS, 1);
                if (p < MSORT) sortbuf[p] = ((u64)__float_as_uint(s) << 32) | (u32)i;
            }
        }
        __syncthreads();
        int K = cntS; if (K > BOXCAP) K = BOXCAP;
        int M = 64; while (M < K) M <<= 1;
        for (int p = K + tid; p < M; p += TPBF) sortbuf[p] = 0;
        __syncthreads();
        for (int kk = 2; kk <= M; kk <<= 1) {
            for (int j = kk >> 1; j > 0; j >>= 1) {
                for (int i = tid; i < M; i += TPBF) {
                    int ixj = i ^ j;
                    if (ixj > i) {
                        u64 a = sortbuf[i], b = sortbuf[ixj];
                        if (((i & kk) == 0) ? (a < b) : (a > b)) { sortbuf[i] = b; sortbuf[ixj] = a; }
                    }
                }
                __syncthreads();
            }
        }
        u32 myIdx[MSORT / TPBF];
        #pragma unroll
        for (int t = 0; t < MSORT / TPBF; t++) myIdx[t] = (u32)sortbuf[t * TPBF + tid];
        __syncthreads();
        u32* gsi_c = gsi + (size_t)c * BOXCAP;
        #pragma unroll
        for (int t = 0; t < MSORT / TPBF; t++) {
            int r = t * TPBF + tid;
            if (r < K) {
                u32 idx = myIdx[t];
                gsi_c[r] = idx;
                boxesLds[r] = ((const float4*)bboxes)[idx];
            }
        }
        if (tid == 0) { ctl[0] = 0; ctl[1] = 0; ctl[2] = 0; }
        __syncthreads();

        if (tid < 256) {
            const int wave = tid >> 6;
            const u32 tb = __float_as_uint(nmsT);
            const float Tn = __uint_as_float(tb + 1u);
            const double B = ((double)nmsT + (double)Tn) * 0.5;
            const bool geCmp = (((tb + 1u) & 1u) == 0u);
            const int smax = (K + 63) >> 6;

            int ret = geCmp ? greedy_full<true >(boxesLds, keptR, pubBox, ctl, gsi_c, rowT, thetaBits, K, smax, B, lane, wave)
                            : greedy_full<false>(boxesLds, keptR, pubBox, ctl, gsi_c, rowT, thetaBits, K, smax, B, lane, wave);
            if (ret >= 0) {
                int kept = ret; if (kept > KPC) kept = KPC;
                for (int p = lane; p < kept; p += 64) {
                    int rank = keptR[p];
                    u32 idx = gsi_c[rank];
                    float sc = rowT[idx];
                    u32 flat = (u32)c * (u32)N + idx;
                    gkept_c[p] = ((u64)__float_as_uint(sc) << 32) | (u32)(~flat);
                }
                if (lane == 0) gNk[c] = (u32)kept;   // published by RELEASE arrival
            }
        }
    }

    // ---- fan-in: RELEASE only if this block rewrote gkept; RELAXED otherwise
    __syncthreads();
    if (tid == 0) {
        u32 v = need ? __hip_atomic_fetch_add(gDone, 1u, __ATOMIC_RELEASE, DEV_SCOPE)
                     : __hip_atomic_fetch_add(gDone, 1u, __ATOMIC_RELAXED, DEV_SCOPE);
        lastS = (v == (u32)(gridDim.x - 1)) ? 1 : 0;
    }
    __syncthreads();
    if (!lastS) return;
    if (tid == 0) {                     // single acquire (cache-inv, no writeback)
        __hip_atomic_fetch_add(gDone, 0u, __ATOMIC_ACQUIRE, DEV_SCOPE);
        nRerunS = (int)__hip_atomic_load(gRerun, __ATOMIC_ACQUIRE, DEV_SCOPE);
    }
    __syncthreads();

    // ---- last block: count-gated candidate assembly from gkept
    u64* selL  = (u64*)smem;                    // 8 KB
    u32* hist4 = (u32*)(smem + 8192);           // 8 KB
    u32* nkL   = (u32*)(smem + 16384);          // nc u32 counts
    const int nc = (int)gridDim.x;
    const int total = nc * KPC;

    for (int c2 = tid; c2 < nc; c2 += TPBF) nkL[c2] = gNk[c2];
    __syncthreads();

    int bstar;
    if (nRerunS == 0) {
        // gHist is exactly the histogram of gkept -> thBs == bstar (r3-r5 phase T)
        bstar = thBsL;
    } else {
        // reruns mutated gkept: recompute bstar over count-gated keys
        for (int b = tid; b < 2048; b += TPBF) hist4[b] = 0;
        __syncthreads();
        for (int t = tid; t < total; t += TPBF) {
            int cc = t / KPC, j = t - cc * KPC;
            if (j < (int)nkL[cc]) {
                u64 k = gkept[t];
                atomicAdd(&hist4[scoreBin((u32)(k >> 32))], 1u);
            }
        }
        __syncthreads();
        bstar_wave0(hist4, Mout, tid, &bs4S, nullptr);
        __syncthreads();
        bstar = bs4S;
    }

    // ONE ballot-compacted count-gated pass: keys with bin >= bstar -> selL
    if (tid == 0) selCountS = 0;
    __syncthreads();
    for (int t = tid; t < total; t += TPBF) {
        int cc = t / KPC, j = t - cc * KPC;
        bool pass = (j < (int)nkL[cc]);
        u64 k = 0;
        if (pass) {
            k = gkept[t];
            pass = (scoreBin((u32)(k >> 32)) >= bstar);
        }
        u64 m = __ballot(pass);
        if (m) {
            int leader = (int)__builtin_ctzll(m);
            int base = 0;
            if (lane == leader) base = atomicAdd(&selCountS, (int)__popcll(m));
            base = __shfl(base, leader, 64);
            if (pass) {
                int p = base + (int)__popcll(m & ((1ull << lane) - 1ull));
                if (p < SELCAP) selL[p] = k;
            }
        }
    }
    __syncthreads();
    int cnt = selCountS; if (cnt > SELCAP) cnt = SELCAP;

    // ---- rank-by-count sort (keys unique) + output
    if (cnt < Mout) {                               // prefill only when short
        for (int t = tid; t < Mout; t += TPBF) {
            out[t * 5 + 0] = 0.f; out[t * 5 + 1] = 0.f; out[t * 5 + 2] = 0.f;
            out[t * 5 + 3] = 0.f; out[t * 5 + 4] = 0.f;
            out[Mout * 5 + t] = -1.0f;
        }
    }
    __syncthreads();
    if (tid < cnt) {
        u64 my = selL[tid];
        int rank = 0;
        for (int j = 0; j < cnt; j++) rank += (selL[j] > my);   // broadcast reads
        if (rank < Mout) {
            float s  = __uint_as_float((u32)(my >> 32));
            u32 flat = ~((u32)my);
            int cc   = (int)(flat / (u32)N);
            int box  = (int)(flat - (u32)cc * (u32)N);
            float4 bb = ((const float4*)bboxes)[box];
            out[rank * 5 + 0] = bb.x;
            out[rank * 5 + 1] = bb.y;
            out[rank * 5 + 2] = bb.z;
            out[rank * 5 + 3] = bb.w;
            out[rank * 5 + 4] = s;
            out[Mout * 5 + rank] = (float)(cc + 1);
        }
    }
}

extern "C" void kernel_launch(void* const* d_in, const int* in_sizes, int n_in,
                              void* d_out, int out_size, void* d_ws, size_t ws_size,
                              hipStream_t stream) {
    const float* bboxes = (const float*)d_in[0];
    const float* scores = (const float*)d_in[1];
    const float* conf   = (const float*)d_in[2];
    const float* nmsT   = (const float*)d_in[3];

    const int N    = in_sizes[0] / 4;        // 5000
    const int C    = in_sizes[1] / N;        // 81
    const int nc   = C - 1;                  // 80
    const int Mout = out_size / 6;           // 300

    // ws layout: [scoresT][gsi][gkept][gK|g65|gPre][gHist(2048)|gDone|gRerun|pad|gNk(nc)]
    char* wsb = (char*)d_ws;
    size_t off = 0;
    float* scoresT = (float*)(wsb + off); off += ((size_t)C * N * sizeof(float) + 255) & ~(size_t)255;
    u32* gsi   = (u32*)(wsb + off); off += (size_t)nc * BOXCAP * sizeof(u32);
    u64* gkept = (u64*)(wsb + off); off += (size_t)nc * KPC * sizeof(u64);
    u32* gK    = (u32*)(wsb + off); off += (size_t)((nc + 1) & ~1) * sizeof(u32);
    u32* g65   = (u32*)(wsb + off); off += (size_t)((nc + 1) & ~1) * sizeof(u32);
    u32* gPre  = (u32*)(wsb + off); off += (size_t)((nc + 1) & ~1) * sizeof(u32);
    u32* gHist = (u32*)(wsb + off); off += 2052 * sizeof(u32);
    u32* gDone  = gHist + 2048;
    u32* gRerun = gHist + 2049;
    u32* gNk   = (u32*)(wsb + off); off += (size_t)((nc + 1) & ~1) * sizeof(u32);

    const int ntile = (N + TBOX - 1) / TBOX;
    transpose_kernel<<<ntile, 1024, 0, stream>>>(scores, N, C, scoresT, gHist);
    nms_select_kernel<<<nc, TPB1, 0, stream>>>(bboxes, scoresT, conf, nmsT, N,
                                               gkept, gK, g65, gPre, gHist, gNk);
    nms_finale_kernel<<<nc, TPBF, 0, stream>>>(bboxes, scoresT, conf, nmsT, N,
                                               gHist, gK, g65, gPre, gsi, gkept,
                                               Mout, (float*)d_out, gDone, gRerun, gNk);
}